// Round 5
// baseline (770.359 us; speedup 1.0000x reference)
//
#include <hip/hip_runtime.h>
#include <hip/hip_bf16.h>

#define EPSV 1e-5f

namespace {
constexpr int Bn = 32, Sn = 1024, Dn = 768, Gn = 8, Cn = 64, Pn = 384;
constexpr int EFn = 1536, GFSn = 192, Nrows = Bn * Sn;  // 32768
}

typedef __attribute__((ext_vector_type(8))) short short8;
typedef __attribute__((ext_vector_type(4))) float f32x4;
typedef __attribute__((ext_vector_type(16))) float f32x16;

__device__ __forceinline__ ushort f2bf(float f) {
  uint u = __builtin_bit_cast(uint, f);
  uint r = (u + 0x7fffu + ((u >> 16) & 1u)) >> 16;
  return (ushort)r;
}
__device__ __forceinline__ uint pack2bf(float lo, float hi) {
  return (uint)f2bf(lo) | ((uint)f2bf(hi) << 16);
}
__device__ __forceinline__ float bf2f(ushort h) {
  return __builtin_bit_cast(float, (uint)h << 16);
}
__device__ __forceinline__ void load16(const ushort* g, ushort* l) {
  __builtin_amdgcn_global_load_lds(
      (const __attribute__((address_space(1))) void*)g,
      (__attribute__((address_space(3))) void*)l, 16, 0, 0);
}
// T1 bijective XCD swizzle (m204): consecutive lid -> same XCD
__device__ __forceinline__ int xcd_lid() {
  const int nbx = gridDim.x;
  const int nwg = nbx * gridDim.y;
  const int orig = blockIdx.y * nbx + blockIdx.x;
  const int xq = nwg >> 3, xr = nwg & 7;
  const int xcd = orig & 7, xi = orig >> 3;
  return (xcd < xr ? xcd * (xq + 1) : xr * (xq + 1) + (xcd - xr) * xq) + xi;
}

// ---------------------------------------------------------------------------
// bf16 MFMA GEMM: 128x128 tile, BK=32, 4 waves (2x2), 2-phase prefetch
// (double-buffered LDS, one barrier per K-step), XCD swizzle.
// TRANS=1: additionally write C^T (bf16) to Ct with stride M (row=col of C).
// ---------------------------------------------------------------------------
template <int OUT_BF16, int TRANS>
__global__ __launch_bounds__(256) void gemm_bf16(
    const ushort* __restrict__ A, const ushort* __restrict__ BT,
    const float* __restrict__ bias, void* __restrict__ Cout,
    ushort* __restrict__ Ct, int M, int N, int K) {
  __shared__ ushort sh[16384];  // 2 x (As 4096 | Bs 4096); epilogue staging
  const int tid = threadIdx.x;
  const int wave = tid >> 6, lane = tid & 63;
  const int nbx = gridDim.x;
  const int lid = xcd_lid();
  const int gm = (lid / nbx) * 128, gn = (lid % nbx) * 128;
  const int wr = wave >> 1, wc = wave & 1;

  const int c0 = tid, c1 = tid + 256;
  const ushort* gA0 = A + (size_t)(gm + (c0 >> 2)) * K + (c0 & 3) * 8;
  const ushort* gA1 = A + (size_t)(gm + (c1 >> 2)) * K + (c1 & 3) * 8;
  const ushort* gB0 = BT + (size_t)(gn + (c0 >> 2)) * K + (c0 & 3) * 8;
  const ushort* gB1 = BT + (size_t)(gn + (c1 >> 2)) * K + (c1 & 3) * 8;

  f32x4 acc[4][4] = {};
  const int arow = wr * 64 + (lane & 15);
  const int brow = wc * 64 + (lane & 15);
  const int koff = (lane >> 4) * 8;
  const int nk = K >> 5;

#define GB_STAGE(buf, k0)                                  \
  {                                                        \
    load16(gA0 + (k0), &sh[(buf)*8192 + wave * 512]);      \
    load16(gA1 + (k0), &sh[(buf)*8192 + 2048 + wave * 512]); \
    load16(gB0 + (k0), &sh[(buf)*8192 + 4096 + wave * 512]); \
    load16(gB1 + (k0), &sh[(buf)*8192 + 6144 + wave * 512]); \
  }

  GB_STAGE(0, 0);
  __syncthreads();
  for (int t = 0; t < nk; ++t) {
    const int buf = t & 1;
    if (t + 1 < nk) GB_STAGE(buf ^ 1, (t + 1) * 32);
    short8 a[4], b[4];
#pragma unroll
    for (int m = 0; m < 4; ++m)
      a[m] = *reinterpret_cast<const short8*>(
          &sh[buf * 8192 + (arow + m * 16) * 32 + koff]);
#pragma unroll
    for (int n = 0; n < 4; ++n)
      b[n] = *reinterpret_cast<const short8*>(
          &sh[buf * 8192 + 4096 + (brow + n * 16) * 32 + koff]);
#pragma unroll
    for (int m = 0; m < 4; ++m)
#pragma unroll
      for (int n = 0; n < 4; ++n)
        acc[m][n] = __builtin_amdgcn_mfma_f32_16x16x32_bf16(
            a[m], b[n], acc[m][n], 0, 0, 0);
    __syncthreads();
  }
#undef GB_STAGE

  // epilogue: C/D layout col=lane&15, row=(lane>>4)*4+j
  const int crow0 = gm + wr * 64 + (lane >> 4) * 4;
  const int ccol0 = gn + wc * 64 + (lane & 15);
  alignas(8) ushort cb[4][4][4];
#pragma unroll
  for (int m = 0; m < 4; ++m)
#pragma unroll
    for (int n = 0; n < 4; ++n) {
      const int col = ccol0 + n * 16;
      const float bv = bias ? bias[col] : 0.f;
#pragma unroll
      for (int j = 0; j < 4; ++j) {
        const float v = acc[m][n][j] + bv;
        if (OUT_BF16) {
          const ushort h = f2bf(v);
          ((ushort*)Cout)[(size_t)(crow0 + m * 16 + j) * N + col] = h;
          if (TRANS) cb[m][n][j] = h;
        } else {
          ((float*)Cout)[(size_t)(crow0 + m * 16 + j) * N + col] = v;
        }
      }
    }

  if (TRANS) {
    // restage transposed tile through LDS: sh[cl][r], stride 136 (16B-aligned,
    // bank-spread), two 64-col passes; coalesced 16B global stores.
    const int l15 = lane & 15, l4 = lane >> 4;
#pragma unroll
    for (int p = 0; p < 2; ++p) {
      __syncthreads();
      if (wc == p) {
#pragma unroll
        for (int n = 0; n < 4; ++n) {
          const int cl = n * 16 + l15;
#pragma unroll
          for (int m = 0; m < 4; ++m) {
            const int r = wr * 64 + m * 16 + l4 * 4;
            *reinterpret_cast<ushort4*>(&sh[cl * 136 + r]) =
                *reinterpret_cast<const ushort4*>(&cb[m][n][0]);
          }
        }
      }
      __syncthreads();
      const int cl = tid >> 2, seg = tid & 3;  // 64 rows x 4 segs of 32
      const ushort* src = &sh[cl * 136 + seg * 32];
      ushort* dst = Ct + (size_t)(gn + p * 64 + cl) * M + gm + seg * 32;
      *reinterpret_cast<uint4*>(dst) = *reinterpret_cast<const uint4*>(src);
      *reinterpret_cast<uint4*>(dst + 8) =
          *reinterpret_cast<const uint4*>(src + 8);
      *reinterpret_cast<uint4*>(dst + 16) =
          *reinterpret_cast<const uint4*>(src + 16);
      *reinterpret_cast<uint4*>(dst + 24) =
          *reinterpret_cast<const uint4*>(src + 24);
    }
  }
}

// ---------------------------------------------------------------------------
// gemm_sm: actT[512][32768] = softmax-epilogue( WT2 @ fea^T ), 2-phase,
// swizzled. Fuses BN1 + group softmax (64-row group per wr-half) + ga.
// ---------------------------------------------------------------------------
__global__ __launch_bounds__(256) void gemm_sm(
    const ushort* __restrict__ A, const ushort* __restrict__ BT,
    const float* __restrict__ g1, const float* __restrict__ b1,
    const float* __restrict__ m1, const float* __restrict__ v1,
    const float* __restrict__ ga, ushort* __restrict__ actT) {
  constexpr int K = EFn, N = Nrows;
  __shared__ ushort sh[16384];
  __shared__ float sScale[128], sShift[128];
  const int tid = threadIdx.x;
  const int wave = tid >> 6, lane = tid & 63;
  const int nbx = gridDim.x;
  const int lid = xcd_lid();
  const int gm = (lid / nbx) * 128, gn = (lid % nbx) * 128;
  const int wr = wave >> 1, wc = wave & 1;

  if (tid < 128) {
    const int row = gm + tid;
    const float sc = g1[row] * rsqrtf(v1[row] + EPSV);
    sScale[tid] = sc;
    sShift[tid] = b1[row] - m1[row] * sc;
  }

  const int c0 = tid, c1 = tid + 256;
  const ushort* gA0 = A + (size_t)(gm + (c0 >> 2)) * K + (c0 & 3) * 8;
  const ushort* gA1 = A + (size_t)(gm + (c1 >> 2)) * K + (c1 & 3) * 8;
  const ushort* gB0 = BT + (size_t)(gn + (c0 >> 2)) * K + (c0 & 3) * 8;
  const ushort* gB1 = BT + (size_t)(gn + (c1 >> 2)) * K + (c1 & 3) * 8;

  f32x4 acc[4][4] = {};
  const int arow = wr * 64 + (lane & 15);
  const int brow = wc * 64 + (lane & 15);
  const int koff = (lane >> 4) * 8;
  const int nk = K >> 5;

#define SM_STAGE(buf, k0)                                  \
  {                                                        \
    load16(gA0 + (k0), &sh[(buf)*8192 + wave * 512]);      \
    load16(gA1 + (k0), &sh[(buf)*8192 + 2048 + wave * 512]); \
    load16(gB0 + (k0), &sh[(buf)*8192 + 4096 + wave * 512]); \
    load16(gB1 + (k0), &sh[(buf)*8192 + 6144 + wave * 512]); \
  }

  SM_STAGE(0, 0);
  __syncthreads();
  for (int t = 0; t < nk; ++t) {
    const int buf = t & 1;
    if (t + 1 < nk) SM_STAGE(buf ^ 1, (t + 1) * 32);
    short8 a[4], b[4];
#pragma unroll
    for (int m = 0; m < 4; ++m)
      a[m] = *reinterpret_cast<const short8*>(
          &sh[buf * 8192 + (arow + m * 16) * 32 + koff]);
#pragma unroll
    for (int n = 0; n < 4; ++n)
      b[n] = *reinterpret_cast<const short8*>(
          &sh[buf * 8192 + 4096 + (brow + n * 16) * 32 + koff]);
#pragma unroll
    for (int m = 0; m < 4; ++m)
#pragma unroll
      for (int n = 0; n < 4; ++n)
        acc[m][n] = __builtin_amdgcn_mfma_f32_16x16x32_bf16(
            a[m], b[n], acc[m][n], 0, 0, 0);
    __syncthreads();
  }
#undef SM_STAGE

  // epilogue: BN1 affine -> softmax over 64 rows (this wr-group) -> *ga
  const int l15 = lane & 15, l4 = lane >> 4;
  const int g = (gm >> 6) + wr;
#pragma unroll
  for (int n = 0; n < 4; ++n) {
    const int col = gn + wc * 64 + n * 16 + l15;
    float mx = -1e30f;
#pragma unroll
    for (int m = 0; m < 4; ++m)
#pragma unroll
      for (int j = 0; j < 4; ++j) {
        const int rl = wr * 64 + m * 16 + l4 * 4 + j;
        acc[m][n][j] = acc[m][n][j] * sScale[rl] + sShift[rl];
        mx = fmaxf(mx, acc[m][n][j]);
      }
    mx = fmaxf(mx, __shfl_xor(mx, 16));
    mx = fmaxf(mx, __shfl_xor(mx, 32));
    float sum = 0.f;
#pragma unroll
    for (int m = 0; m < 4; ++m)
#pragma unroll
      for (int j = 0; j < 4; ++j) {
        acc[m][n][j] = expf(acc[m][n][j] - mx);
        sum += acc[m][n][j];
      }
    sum += __shfl_xor(sum, 16);
    sum += __shfl_xor(sum, 32);
    const float sc = ga[(size_t)col * 8 + g] / sum;
#pragma unroll
    for (int m = 0; m < 4; ++m)
#pragma unroll
      for (int j = 0; j < 4; ++j) {
        const int rowg = gm + wr * 64 + m * 16 + l4 * 4 + j;
        actT[(size_t)rowg * N + col] = f2bf(acc[m][n][j] * sc);
      }
  }
}

// ---------------------------------------------------------------------------
// f32 -> bf16 convert
// ---------------------------------------------------------------------------
__global__ __launch_bounds__(256) void cvt_kernel(const float* __restrict__ in,
                                                  ushort* __restrict__ out,
                                                  int n4) {
  const int i = blockIdx.x * 256 + threadIdx.x;
  if (i >= n4) return;
  const float4 v = reinterpret_cast<const float4*>(in)[i];
  ushort4 o;
  o.x = f2bf(v.x); o.y = f2bf(v.y); o.z = f2bf(v.z); o.w = f2bf(v.w);
  reinterpret_cast<ushort4*>(out)[i] = o;
}

// ---------------------------------------------------------------------------
// transpose + convert: in f32 [R][C] -> out bf16 [C][R]
// ---------------------------------------------------------------------------
__global__ __launch_bounds__(256) void tconv_kernel(const float* __restrict__ in,
                                                    ushort* __restrict__ out,
                                                    int R, int C) {
  __shared__ float t[32][33];
  const int tx = threadIdx.x & 31, ty = threadIdx.x >> 5;
  const int bc = blockIdx.x * 32, br = blockIdx.y * 32;
#pragma unroll
  for (int i = 0; i < 32; i += 8)
    t[ty + i][tx] = in[(size_t)(br + ty + i) * C + bc + tx];
  __syncthreads();
#pragma unroll
  for (int i = 0; i < 32; i += 8)
    out[(size_t)(bc + ty + i) * R + br + tx] = f2bf(t[tx][ty + i]);
}

// ---------------------------------------------------------------------------
// f32 SGEMM for the small GEMMs (nc, kv). MODE 1: BN2 epilogue.
// MODE 2: kv split -> k_bf [2048][384] bf16, vT_bf [32][384][64] bf16
// ---------------------------------------------------------------------------
template <int MODE>
__global__ __launch_bounds__(256) void sgemm128(
    const float* __restrict__ A, const float* __restrict__ Bm,
    const float* __restrict__ bias, float* __restrict__ C,
    int M, int N, int K,
    const float* __restrict__ g2, const float* __restrict__ b2,
    const float* __restrict__ m2, const float* __restrict__ v2,
    ushort* __restrict__ kq, ushort* __restrict__ vt) {
  __shared__ float As[16][128];
  __shared__ float Bs[16][128];
  const int tid = threadIdx.x;
  const int tx = tid & 15, ty = tid >> 4;
  const int gm = blockIdx.y * 128, gn = blockIdx.x * 128;
  float acc[8][8] = {};

  for (int k0 = 0; k0 < K; k0 += 16) {
#pragma unroll
    for (int i = 0; i < 2; ++i) {
      const int idx = tid + i * 256;
      const int row = idx >> 2, kqq = idx & 3;
      const float4 av = *reinterpret_cast<const float4*>(
          &A[(size_t)(gm + row) * K + k0 + kqq * 4]);
      As[kqq * 4 + 0][row] = av.x;
      As[kqq * 4 + 1][row] = av.y;
      As[kqq * 4 + 2][row] = av.z;
      As[kqq * 4 + 3][row] = av.w;
      const int kr = idx >> 5, cq = idx & 31;
      *reinterpret_cast<float4*>(&Bs[kr][cq * 4]) =
          *reinterpret_cast<const float4*>(
              &Bm[(size_t)(k0 + kr) * N + gn + cq * 4]);
    }
    __syncthreads();
#pragma unroll
    for (int k = 0; k < 16; ++k) {
      alignas(16) float a[8], b[8];
      *reinterpret_cast<float4*>(&a[0]) =
          *reinterpret_cast<const float4*>(&As[k][ty * 4]);
      *reinterpret_cast<float4*>(&a[4]) =
          *reinterpret_cast<const float4*>(&As[k][64 + ty * 4]);
      *reinterpret_cast<float4*>(&b[0]) =
          *reinterpret_cast<const float4*>(&Bs[k][tx * 4]);
      *reinterpret_cast<float4*>(&b[4]) =
          *reinterpret_cast<const float4*>(&Bs[k][64 + tx * 4]);
#pragma unroll
      for (int i = 0; i < 8; ++i)
#pragma unroll
        for (int j = 0; j < 8; ++j) acc[i][j] += a[i] * b[j];
    }
    __syncthreads();
  }

#pragma unroll
  for (int i = 0; i < 8; ++i) {
    const int row = gm + ty * 4 + (i & 3) + (i >> 2) * 64;
    float scale = 1.f, shift = 0.f;
    if (MODE == 1) {
      const int c = row & 63;
      scale = g2[c] * rsqrtf(v2[c] + EPSV);
      shift = b2[c] - m2[c] * scale;
    }
#pragma unroll
    for (int jh = 0; jh < 2; ++jh) {
      const int cb = gn + tx * 4 + jh * 64;
      alignas(16) float o[4];
#pragma unroll
      for (int j = 0; j < 4; ++j) {
        float v = acc[i][jh * 4 + j];
        if (bias) v += bias[cb + j];
        if (MODE == 1) v = v * scale + shift;
        o[j] = v;
      }
      if (MODE == 2) {
        if (cb < 384) {
          ushort4 ov;
          ov.x = f2bf(o[0]); ov.y = f2bf(o[1]);
          ov.z = f2bf(o[2]); ov.w = f2bf(o[3]);
          *reinterpret_cast<ushort4*>(&kq[(size_t)row * 384 + cb]) = ov;
        } else {
          const int b = row >> 6, c = row & 63;
#pragma unroll
          for (int j = 0; j < 4; ++j)
            vt[(size_t)b * 24576 + (size_t)(cb - 384 + j) * 64 + c] =
                f2bf(o[j]);
        }
      } else {
        *reinterpret_cast<float4*>(&C[(size_t)row * N + cb]) =
            *reinterpret_cast<const float4*>(o);
      }
    }
  }
}

// ---------------------------------------------------------------------------
// ga = sigmoid(fea @ W_ga + b_ga) : one wave per row, short8-vectorized
// ---------------------------------------------------------------------------
__global__ __launch_bounds__(256) void ga_kernel(
    const ushort* __restrict__ fea, const float* __restrict__ W_ga,
    const float* __restrict__ b_ga, float* __restrict__ ga) {
  const int w = threadIdx.x >> 6, lane = threadIdx.x & 63;
  const int n = blockIdx.x * 4 + w;
  const ushort* fr = fea + (size_t)n * EFn;
  float acc[8] = {};
#pragma unroll
  for (int it = 0; it < 3; ++it) {
    const int kb = it * 512 + lane * 8;
    const short8 f8 = *reinterpret_cast<const short8*>(&fr[kb]);
#pragma unroll
    for (int j = 0; j < 8; ++j) {
      const float f = bf2f((ushort)f8[j]);
      const float4 w0 =
          *reinterpret_cast<const float4*>(&W_ga[(size_t)(kb + j) * 8]);
      const float4 w1 =
          *reinterpret_cast<const float4*>(&W_ga[(size_t)(kb + j) * 8 + 4]);
      acc[0] += f * w0.x; acc[1] += f * w0.y;
      acc[2] += f * w0.z; acc[3] += f * w0.w;
      acc[4] += f * w1.x; acc[5] += f * w1.y;
      acc[6] += f * w1.z; acc[7] += f * w1.w;
    }
  }
#pragma unroll
  for (int g = 0; g < 8; ++g) {
    float v = acc[g];
#pragma unroll
    for (int off = 32; off; off >>= 1) v += __shfl_xor(v, off);
    acc[g] = v;
  }
  if (lane < 8) {
    float v = acc[0];
#pragma unroll
    for (int g = 1; g < 8; ++g) v = (lane == g) ? acc[g] : v;
    v += b_ga[lane];
    ga[(size_t)n * 8 + lane] = 1.0f / (1.0f + expf(-v));
  }
}

// ---------------------------------------------------------------------------
// cent_mfma: block per (b,g). part[b*8+g][c=64][f=192], K=1024 over s.
// ---------------------------------------------------------------------------
__global__ __launch_bounds__(256) void cent_mfma(
    const ushort* __restrict__ actT, const ushort* __restrict__ feaT,
    float* __restrict__ part) {
  __shared__ ushort As[2][64 * 64];
  __shared__ ushort Bs[2][192 * 64];
  const int tid = threadIdx.x;
  const int wave = tid >> 6, lane = tid & 63;
  const int b = blockIdx.x >> 3, g = blockIdx.x & 7;
  const size_t colbase = (size_t)b * 1024;
  const int srow = tid >> 2, scp = (tid & 3) * 2;
  const ushort* gA = actT + (size_t)(g * 64 + srow) * Nrows + colbase;
  const ushort* gB0 = feaT + (size_t)(g * 192 + srow) * Nrows + colbase;
  const ushort* gB1 = gB0 + (size_t)64 * Nrows;
  const ushort* gB2 = gB0 + (size_t)128 * Nrows;

  uint4 ra[2], rb0[2], rb1[2], rb2[2];
  f32x4 acc[4][3] = {};
  const int l15 = lane & 15, hi = lane >> 4;
  const int sw = srow & 7;

#define CM_ISSUE(k0)                                                    \
  {                                                                     \
    _Pragma("unroll") for (int i = 0; i < 2; ++i) {                     \
      const int off = (k0) + (scp + i) * 8;                             \
      ra[i] = *reinterpret_cast<const uint4*>(gA + off);                \
      rb0[i] = *reinterpret_cast<const uint4*>(gB0 + off);              \
      rb1[i] = *reinterpret_cast<const uint4*>(gB1 + off);              \
      rb2[i] = *reinterpret_cast<const uint4*>(gB2 + off);              \
    }                                                                   \
  }
#define CM_STASH(buf)                                                   \
  {                                                                     \
    _Pragma("unroll") for (int i = 0; i < 2; ++i) {                     \
      const int c = scp + i;                                            \
      *reinterpret_cast<uint4*>(&As[buf][srow * 64 + ((c ^ sw) * 8)]) = \
          ra[i];                                                        \
      *reinterpret_cast<uint4*>(&Bs[buf][srow * 64 + ((c ^ sw) * 8)]) = \
          rb0[i];                                                       \
      *reinterpret_cast<uint4*>(                                        \
          &Bs[buf][(64 + srow) * 64 + ((c ^ sw) * 8)]) = rb1[i];        \
      *reinterpret_cast<uint4*>(                                        \
          &Bs[buf][(128 + srow) * 64 + ((c ^ sw) * 8)]) = rb2[i];       \
    }                                                                   \
  }

  CM_ISSUE(0);
  CM_STASH(0);
  for (int kk = 0; kk < 16; ++kk) {
    const int buf = kk & 1;
    if (kk < 15) CM_ISSUE((kk + 1) * 64);
    __syncthreads();
#pragma unroll
    for (int ks = 0; ks < 2; ++ks) {
      const int ch = ks * 4 + hi;
      short8 a[4], bb[3];
#pragma unroll
      for (int m = 0; m < 4; ++m) {
        const int r = m * 16 + l15;
        a[m] = *reinterpret_cast<const short8*>(
            &As[buf][r * 64 + ((ch ^ (r & 7)) * 8)]);
      }
#pragma unroll
      for (int nn = 0; nn < 3; ++nn) {
        const int r = wave * 48 + nn * 16 + l15;
        bb[nn] = *reinterpret_cast<const short8*>(
            &Bs[buf][r * 64 + ((ch ^ (r & 7)) * 8)]);
      }
#pragma unroll
      for (int m = 0; m < 4; ++m)
#pragma unroll
        for (int nn = 0; nn < 3; ++nn)
          acc[m][nn] = __builtin_amdgcn_mfma_f32_16x16x32_bf16(
              a[m], bb[nn], acc[m][nn], 0, 0, 0);
    }
    if (kk < 15) CM_STASH(buf ^ 1);
  }
#undef CM_ISSUE
#undef CM_STASH

  float* pb = part + (size_t)blockIdx.x * 12288;
#pragma unroll
  for (int m = 0; m < 4; ++m)
#pragma unroll
    for (int nn = 0; nn < 3; ++nn) {
      const int col = wave * 48 + nn * 16 + l15;
#pragma unroll
      for (int j = 0; j < 4; ++j) {
        const int row = m * 16 + hi * 4 + j;
        pb[row * 192 + col] = acc[m][nn][j];
      }
    }
}

__global__ __launch_bounds__(256) void cent_reduce8(
    const float* __restrict__ part, float* __restrict__ cent) {
  const int idx = blockIdx.x * 256 + threadIdx.x;  // < 393216
  const int b = idx / 12288, r = idx % 12288;
  float s = 0.f;
#pragma unroll
  for (int g = 0; g < 8; ++g) s += part[(size_t)(b * 8 + g) * 12288 + r];
  cent[idx] = s;
}

// ---------------------------------------------------------------------------
// MFMA attention (verified R3): one wave per 32 q-rows, all-register.
// ---------------------------------------------------------------------------
__global__ __launch_bounds__(256) void attn_mfma(
    const ushort* __restrict__ qb, const ushort* __restrict__ kb,
    const ushort* __restrict__ vtb, ushort* __restrict__ aout) {
  const int wave = threadIdx.x >> 6, lane = threadIdx.x & 63;
  const int wrow = blockIdx.x * 4 + wave;
  const int row0 = wrow * 32;
  const int b = row0 >> 10;
  const int l31 = lane & 31, hi = lane >> 5;

  f32x16 accs0 = 0.f, accs1 = 0.f;
  const ushort* qp = qb + (size_t)(row0 + l31) * 384 + hi * 8;
  const ushort* kp = kb + (size_t)(b * 64 + l31) * 384 + hi * 8;
#pragma unroll 4
  for (int ks = 0; ks < 24; ++ks) {
    const short8 bq = *reinterpret_cast<const short8*>(qp + ks * 16);
    const short8 a0 = *reinterpret_cast<const short8*>(kp + ks * 16);
    const short8 a1 = *reinterpret_cast<const short8*>(kp + 32 * 384 + ks * 16);
    accs0 = __builtin_amdgcn_mfma_f32_32x32x16_bf16(a0, bq, accs0, 0, 0, 0);
    accs1 = __builtin_amdgcn_mfma_f32_32x32x16_bf16(a1, bq, accs1, 0, 0, 0);
  }

  const float alpha = 0.05103103630798287f;
  float p[32];
#pragma unroll
  for (int i = 0; i < 16; ++i) { p[i] = accs0[i]; p[16 + i] = accs1[i]; }
  float mx = p[0];
#pragma unroll
  for (int i = 1; i < 32; ++i) mx = fmaxf(mx, p[i]);
  mx = fmaxf(mx, __shfl_xor(mx, 32));
  float sum = 0.f;
#pragma unroll
  for (int i = 0; i < 32; ++i) {
    p[i] = expf((p[i] - mx) * alpha);
    sum += p[i];
  }
  sum += __shfl_xor(sum, 32);
  const float inv = 1.0f / sum;

  uint pk0[8], pk1[8];
#pragma unroll
  for (int ct = 0; ct < 2; ++ct)
#pragma unroll
    for (int rg = 0; rg < 4; ++rg) {
      pk0[ct * 4 + rg] =
          pack2bf(p[ct * 16 + rg * 4 + 0] * inv, p[ct * 16 + rg * 4 + 1] * inv);
      pk1[ct * 4 + rg] =
          pack2bf(p[ct * 16 + rg * 4 + 2] * inv, p[ct * 16 + rg * 4 + 3] * inv);
    }
  uint ex0[8], ex1[8];
#pragma unroll
  for (int i = 0; i < 8; ++i) {
    ex0[i] = __shfl_xor(pk0[i], 32);
    ex1[i] = __shfl_xor(pk1[i], 32);
  }

  const ushort* vp = vtb + ((size_t)b * 384 + l31) * 64 + hi * 8;
  ushort* orow = aout + (size_t)(row0 + l31) * 384;
  for (int mt = 0; mt < 12; ++mt) {
    f32x16 acco = 0.f;
#pragma unroll
    for (int kc = 0; kc < 4; ++kc) {
      const short8 av = *reinterpret_cast<const short8*>(
          vp + (size_t)mt * 32 * 64 + kc * 16);
      const int base = (kc >> 1) * 4 + (kc & 1) * 2;
      const uint o0 = hi ? pk0[base + 1] : pk0[base];
      const uint o1 = hi ? pk1[base + 1] : pk1[base];
      const uint e0 = hi ? ex0[base + 1] : ex0[base];
      const uint e1 = hi ? ex1[base + 1] : ex1[base];
      uint4 uu;
      uu.x = hi ? e0 : o0;
      uu.y = hi ? e1 : o1;
      uu.z = hi ? o0 : e0;
      uu.w = hi ? o1 : e1;
      const short8 bp = __builtin_bit_cast(short8, uu);
      acco = __builtin_amdgcn_mfma_f32_32x32x16_bf16(av, bp, acco, 0, 0, 0);
    }
#pragma unroll
    for (int rg = 0; rg < 4; ++rg) {
      ushort4 ov;
      ov.x = f2bf(acco[rg * 4 + 0]);
      ov.y = f2bf(acco[rg * 4 + 1]);
      ov.z = f2bf(acco[rg * 4 + 2]);
      ov.w = f2bf(acco[rg * 4 + 3]);
      *reinterpret_cast<ushort4*>(&orow[mt * 32 + rg * 8 + hi * 4]) = ov;
    }
  }
}

// ---------------------------------------------------------------------------
extern "C" void kernel_launch(void* const* d_in, const int* in_sizes, int n_in,
                              void* d_out, int out_size, void* d_ws,
                              size_t ws_size, hipStream_t stream) {
  (void)in_sizes; (void)n_in; (void)out_size; (void)ws_size;
  const float* x      = (const float*)d_in[0];
  const float* W_exp  = (const float*)d_in[1];
  const float* b_exp  = (const float*)d_in[2];
  const float* W_ga   = (const float*)d_in[3];
  const float* b_ga   = (const float*)d_in[4];
  const float* bn1_g  = (const float*)d_in[5];
  const float* bn1_b  = (const float*)d_in[6];
  const float* bn1_m  = (const float*)d_in[7];
  const float* bn1_v  = (const float*)d_in[8];
  const float* cw     = (const float*)d_in[9];
  const float* W_proj = (const float*)d_in[10];
  const float* b_proj = (const float*)d_in[11];
  const float* bn2_g  = (const float*)d_in[12];
  const float* bn2_b  = (const float*)d_in[13];
  const float* bn2_m  = (const float*)d_in[14];
  const float* bn2_v  = (const float*)d_in[15];
  const float* Wq     = (const float*)d_in[16];
  const float* bq     = (const float*)d_in[17];
  const float* Wkv    = (const float*)d_in[18];
  const float* bkv    = (const float*)d_in[19];
  const float* Wp2    = (const float*)d_in[20];
  const float* bp2    = (const float*)d_in[21];
  float* out = (float*)d_out;

  char* ws = (char*)d_ws;
  // region A @0: fea bf16 100.66MB [3..8]; aout bf16 25.2MB [11..12]
  ushort* fea  = (ushort*)(ws + 0);
  ushort* aout = (ushort*)(ws + 0);
  // region B @100663296: xb 50.3MB [1..4]; actT bf16 33.6MB [7..8]
  ushort* xb   = (ushort*)(ws + 100663296ull);
  ushort* actT = (ushort*)(ws + 100663296ull);
  ushort* q_bf = (ushort*)(ws + 150994944ull);  // 25.2MB [4..11]
  float*  ga   = (float*)(ws + 176160768ull);   // 1MB    [5..7]
  float*  part = (float*)(ws + 177209344ull);   // 12.6MB [8]
  float*  cent = (float*)(ws + 189792256ull);   // 1.5MB  [8..9]
  float*  nc   = (float*)(ws + 191365120ull);   // 6.3MB  [9..10]
  ushort* k_bf = (ushort*)(ws + 197656576ull);  // 1.5MB  [10..11]
  ushort* vT_bf= (ushort*)(ws + 199229440ull);  // 1.5MB  [10..11]
  ushort* WT1  = (ushort*)(ws + 200802304ull);
  ushort* WT2  = (ushort*)(ws + 203161600ull);
  ushort* WT3  = (ushort*)(ws + 204734464ull);
  ushort* WT4  = (ushort*)(ws + 205324288ull);
  // feaT lives in d_out (exactly 100,663,296 bytes), dead before final GEMM
  ushort* feaT = (ushort*)d_out;

  dim3 blk(256);
  // 1. conversions
  cvt_kernel<<<dim3((Nrows * Dn / 4 + 255) / 256), blk, 0, stream>>>(
      x, xb, Nrows * Dn / 4);
  tconv_kernel<<<dim3(EFn / 32, Dn / 32), blk, 0, stream>>>(W_exp, WT1, Dn, EFn);
  tconv_kernel<<<dim3(512 / 32, EFn / 32), blk, 0, stream>>>(cw, WT2, EFn, 512);
  tconv_kernel<<<dim3(Pn / 32, Dn / 32), blk, 0, stream>>>(Wq, WT3, Dn, Pn);
  tconv_kernel<<<dim3(Dn / 32, Pn / 32), blk, 0, stream>>>(Wp2, WT4, Pn, Dn);
  // 3. fea = bf16(x @ W_exp + b_exp); also writes feaT (fused transpose)
  gemm_bf16<1, 1><<<dim3(EFn / 128, Nrows / 128), blk, 0, stream>>>(
      xb, WT1, b_exp, fea, feaT, Nrows, EFn, Dn);
  // 4. q = bf16(x @ Wq + bq)   (last consumer of xb)
  gemm_bf16<1, 0><<<dim3(Pn / 128, Nrows / 128), blk, 0, stream>>>(
      xb, WT3, bq, q_bf, nullptr, Nrows, Pn, Dn);
  // 5. ga
  ga_kernel<<<dim3(Nrows / 4), blk, 0, stream>>>(fea, W_ga, b_ga, ga);
  // 7. actT = softmax-gemm(cw^T @ fea^T)
  gemm_sm<<<dim3(Nrows / 128, 512 / 128), blk, 0, stream>>>(
      WT2, fea, bn1_g, bn1_b, bn1_m, bn1_v, ga, actT);
  // 8. cent = sum_g actT_g @ feaT_g^T
  cent_mfma<<<dim3(Bn * Gn), blk, 0, stream>>>(actT, feaT, part);
  cent_reduce8<<<dim3(393216 / 256), blk, 0, stream>>>(part, cent);
  // 9. nc = BN2(cent @ W_proj + b_proj)
  sgemm128<1><<<dim3(768 / 128, 2048 / 128), blk, 0, stream>>>(
      cent, W_proj, b_proj, nc, 2048, 768, GFSn, bn2_g, bn2_b, bn2_m, bn2_v,
      nullptr, nullptr);
  // 10. kv GEMM -> k_bf, vT_bf
  sgemm128<2><<<dim3(768 / 128, 2048 / 128), blk, 0, stream>>>(
      nc, Wkv, bkv, nullptr, 2048, 768, Dn, nullptr, nullptr, nullptr, nullptr,
      k_bf, vT_bf);
  // 11. attention
  attn_mfma<<<dim3(Nrows / 128), blk, 0, stream>>>(q_bf, k_bf, vT_bf, aout);
  // 12. out = aout @ Wp2 + bp2  (overwrites feaT scratch)
  gemm_bf16<0, 0><<<dim3(Dn / 128, Nrows / 128), blk, 0, stream>>>(
      aout, WT4, bp2, out, nullptr, Nrows, Dn, Pn);
}

// Round 6
// 512.148 us; speedup vs baseline: 1.5042x; 1.5042x over previous
//
#include <hip/hip_runtime.h>
#include <hip/hip_bf16.h>

#define EPSV 1e-5f

namespace {
constexpr int Bn = 32, Sn = 1024, Dn = 768, Gn = 8, Cn = 64, Pn = 384;
constexpr int EFn = 1536, GFSn = 192, Nrows = Bn * Sn;  // 32768
}

typedef __attribute__((ext_vector_type(8))) short short8;
typedef __attribute__((ext_vector_type(4))) float f32x4;
typedef __attribute__((ext_vector_type(16))) float f32x16;

__device__ __forceinline__ ushort f2bf(float f) {
  uint u = __builtin_bit_cast(uint, f);
  uint r = (u + 0x7fffu + ((u >> 16) & 1u)) >> 16;
  return (ushort)r;
}
__device__ __forceinline__ uint pack2bf(float lo, float hi) {
  return (uint)f2bf(lo) | ((uint)f2bf(hi) << 16);
}
__device__ __forceinline__ float bf2f(ushort h) {
  return __builtin_bit_cast(float, (uint)h << 16);
}
__device__ __forceinline__ void load16(const ushort* g, ushort* l) {
  __builtin_amdgcn_global_load_lds(
      (const __attribute__((address_space(1))) void*)g,
      (__attribute__((address_space(3))) void*)l, 16, 0, 0);
}
// T1 bijective XCD swizzle (m204)
__device__ __forceinline__ int xcd_lid() {
  const int nbx = gridDim.x;
  const int nwg = nbx * gridDim.y;
  const int orig = blockIdx.y * nbx + blockIdx.x;
  const int xq = nwg >> 3, xr = nwg & 7;
  const int xcd = orig & 7, xi = orig >> 3;
  return (xcd < xr ? xcd * (xq + 1) : xr * (xq + 1) + (xcd - xr) * xq) + xi;
}

// ---------------------------------------------------------------------------
// bf16 MFMA GEMM: 128x128 tile, BK=32, 4 waves (2x2), 2-phase prefetch,
// XCD swizzle. Epilogue MODE:
//   0: f32 out (+bias)
//   1: bf16 out (+bias); TRANS=1 additionally writes C^T bf16 to Ct (stride M)
//   2: bf16 out, BN2 affine per row%64 (nc GEMM)
//   3: kv split: col<384 -> kq[row*384+col]; else vt[b][col-384][row%64]
// ---------------------------------------------------------------------------
template <int MODE, int TRANS>
__global__ __launch_bounds__(256) void gemm_bf16(
    const ushort* __restrict__ A, const ushort* __restrict__ BT,
    const float* __restrict__ bias, void* __restrict__ Cout,
    ushort* __restrict__ Ct, int M, int N, int K,
    const float* __restrict__ g2, const float* __restrict__ b2,
    const float* __restrict__ m2, const float* __restrict__ v2,
    ushort* __restrict__ kq, ushort* __restrict__ vt) {
  __shared__ ushort sh[16384];  // 2 x (As 4096 | Bs 4096); epilogue staging
  const int tid = threadIdx.x;
  const int wave = tid >> 6, lane = tid & 63;
  const int nbx = gridDim.x;
  const int lid = xcd_lid();
  const int gm = (lid / nbx) * 128, gn = (lid % nbx) * 128;
  const int wr = wave >> 1, wc = wave & 1;

  const int c0 = tid, c1 = tid + 256;
  const ushort* gA0 = A + (size_t)(gm + (c0 >> 2)) * K + (c0 & 3) * 8;
  const ushort* gA1 = A + (size_t)(gm + (c1 >> 2)) * K + (c1 & 3) * 8;
  const ushort* gB0 = BT + (size_t)(gn + (c0 >> 2)) * K + (c0 & 3) * 8;
  const ushort* gB1 = BT + (size_t)(gn + (c1 >> 2)) * K + (c1 & 3) * 8;

  f32x4 acc[4][4] = {};
  const int arow = wr * 64 + (lane & 15);
  const int brow = wc * 64 + (lane & 15);
  const int koff = (lane >> 4) * 8;
  const int nk = K >> 5;

#define GB_STAGE(buf, k0)                                    \
  {                                                          \
    load16(gA0 + (k0), &sh[(buf)*8192 + wave * 512]);        \
    load16(gA1 + (k0), &sh[(buf)*8192 + 2048 + wave * 512]); \
    load16(gB0 + (k0), &sh[(buf)*8192 + 4096 + wave * 512]); \
    load16(gB1 + (k0), &sh[(buf)*8192 + 6144 + wave * 512]); \
  }

  GB_STAGE(0, 0);
  __syncthreads();
  for (int t = 0; t < nk; ++t) {
    const int buf = t & 1;
    if (t + 1 < nk) GB_STAGE(buf ^ 1, (t + 1) * 32);
    short8 a[4], b[4];
#pragma unroll
    for (int m = 0; m < 4; ++m)
      a[m] = *reinterpret_cast<const short8*>(
          &sh[buf * 8192 + (arow + m * 16) * 32 + koff]);
#pragma unroll
    for (int n = 0; n < 4; ++n)
      b[n] = *reinterpret_cast<const short8*>(
          &sh[buf * 8192 + 4096 + (brow + n * 16) * 32 + koff]);
#pragma unroll
    for (int m = 0; m < 4; ++m)
#pragma unroll
      for (int n = 0; n < 4; ++n)
        acc[m][n] = __builtin_amdgcn_mfma_f32_16x16x32_bf16(
            a[m], b[n], acc[m][n], 0, 0, 0);
    __syncthreads();
  }
#undef GB_STAGE

  // epilogue: C/D layout col=lane&15, row=(lane>>4)*4+j
  const int crow0 = gm + wr * 64 + (lane >> 4) * 4;
  const int ccol0 = gn + wc * 64 + (lane & 15);
  float sc_[4][4], sf_[4][4];
  if (MODE == 2) {
#pragma unroll
    for (int m = 0; m < 4; ++m)
#pragma unroll
      for (int j = 0; j < 4; ++j) {
        const int c = (crow0 + m * 16 + j) & 63;
        const float s = g2[c] * rsqrtf(v2[c] + EPSV);
        sc_[m][j] = s;
        sf_[m][j] = b2[c] - m2[c] * s;
      }
  }
  alignas(8) ushort cb[4][4][4];
#pragma unroll
  for (int m = 0; m < 4; ++m)
#pragma unroll
    for (int n = 0; n < 4; ++n) {
      const int col = ccol0 + n * 16;
      const float bv = bias ? bias[col] : 0.f;
#pragma unroll
      for (int j = 0; j < 4; ++j) {
        const int row = crow0 + m * 16 + j;
        float v = acc[m][n][j] + bv;
        if (MODE == 0) {
          ((float*)Cout)[(size_t)row * N + col] = v;
        } else if (MODE == 1) {
          const ushort h = f2bf(v);
          ((ushort*)Cout)[(size_t)row * N + col] = h;
          if (TRANS) cb[m][n][j] = h;
        } else if (MODE == 2) {
          v = v * sc_[m][j] + sf_[m][j];
          ((ushort*)Cout)[(size_t)row * N + col] = f2bf(v);
        } else {  // MODE 3: kv split
          const ushort h = f2bf(v);
          if (col < 384) {
            kq[(size_t)row * 384 + col] = h;
          } else {
            vt[(size_t)(row >> 6) * 24576 + (size_t)(col - 384) * 64 +
               (row & 63)] = h;
          }
        }
      }
    }

  if (TRANS) {
    // restage transposed tile through LDS (stride 136), coalesced 16B stores
    const int l15 = lane & 15, l4 = lane >> 4;
#pragma unroll
    for (int p = 0; p < 2; ++p) {
      __syncthreads();
      if (wc == p) {
#pragma unroll
        for (int n = 0; n < 4; ++n) {
          const int cl = n * 16 + l15;
#pragma unroll
          for (int m = 0; m < 4; ++m) {
            const int r = wr * 64 + m * 16 + l4 * 4;
            *reinterpret_cast<ushort4*>(&sh[cl * 136 + r]) =
                *reinterpret_cast<const ushort4*>(&cb[m][n][0]);
          }
        }
      }
      __syncthreads();
      const int cl = tid >> 2, seg = tid & 3;
      const ushort* src = &sh[cl * 136 + seg * 32];
      ushort* dst = Ct + (size_t)(gn + p * 64 + cl) * M + gm + seg * 32;
      *reinterpret_cast<uint4*>(dst) = *reinterpret_cast<const uint4*>(src);
      *reinterpret_cast<uint4*>(dst + 8) =
          *reinterpret_cast<const uint4*>(src + 8);
      *reinterpret_cast<uint4*>(dst + 16) =
          *reinterpret_cast<const uint4*>(src + 16);
      *reinterpret_cast<uint4*>(dst + 24) =
          *reinterpret_cast<const uint4*>(src + 24);
    }
  }
}

// ---------------------------------------------------------------------------
// gemm_ga: ga[32768][8] = sigmoid(fea @ W_ga + b_ga) via MFMA.
// 128-row tile x N=16 (W_gaT zero-padded to 16 rows). Wave w owns rows
// w*32..w*32+31 (2 m-frags). Double-buffered, 1 barrier/K-step.
// ---------------------------------------------------------------------------
__global__ __launch_bounds__(256) void gemm_ga(
    const ushort* __restrict__ fea, const ushort* __restrict__ WTga,
    const float* __restrict__ b_ga, float* __restrict__ ga) {
  constexpr int K = EFn;
  __shared__ ushort sh[9216];  // 2 x (As 4096 | Bs 512)
  const int tid = threadIdx.x;
  const int wave = tid >> 6, lane = tid & 63;
  const int gm = blockIdx.x * 128;

  const int c0 = tid, c1 = tid + 256;
  const ushort* gA0 = fea + (size_t)(gm + (c0 >> 2)) * K + (c0 & 3) * 8;
  const ushort* gA1 = fea + (size_t)(gm + (c1 >> 2)) * K + (c1 & 3) * 8;
  const ushort* gB = WTga + (size_t)(lane >> 2) * K + (lane & 3) * 8;

  f32x4 acc[2] = {};
  const int l15 = lane & 15, l4 = lane >> 4;
  const int koff = l4 * 8;

#define GA_STAGE(buf, k0)                                         \
  {                                                               \
    load16(gA0 + (k0), &sh[(buf)*4608 + wave * 512]);             \
    load16(gA1 + (k0), &sh[(buf)*4608 + 2048 + wave * 512]);      \
    if (wave == 0) load16(gB + (k0), &sh[(buf)*4608 + 4096]);     \
  }

  GA_STAGE(0, 0);
  __syncthreads();
  for (int t = 0; t < K / 32; ++t) {
    const int buf = t & 1;
    if (t + 1 < K / 32) GA_STAGE(buf ^ 1, (t + 1) * 32);
    const short8 b = *reinterpret_cast<const short8*>(
        &sh[buf * 4608 + 4096 + l15 * 32 + koff]);
    short8 a[2];
#pragma unroll
    for (int mi = 0; mi < 2; ++mi)
      a[mi] = *reinterpret_cast<const short8*>(
          &sh[buf * 4608 + (wave * 32 + mi * 16 + l15) * 32 + koff]);
#pragma unroll
    for (int mi = 0; mi < 2; ++mi)
      acc[mi] =
          __builtin_amdgcn_mfma_f32_16x16x32_bf16(a[mi], b, acc[mi], 0, 0, 0);
    __syncthreads();
  }
#undef GA_STAGE

  if (l15 < 8) {
    const float bv = b_ga[l15];
#pragma unroll
    for (int mi = 0; mi < 2; ++mi)
#pragma unroll
      for (int j = 0; j < 4; ++j) {
        const int row = gm + wave * 32 + mi * 16 + l4 * 4 + j;
        const float v = acc[mi][j] + bv;
        ga[(size_t)row * 8 + l15] = 1.0f / (1.0f + expf(-v));
      }
  }
}

// ---------------------------------------------------------------------------
// gemm_sm: actT[512][32768] = softmax-epilogue( WT2 @ fea^T ), 2-phase,
// swizzled. Fuses BN1 + group softmax (64-row group per wr-half) + ga.
// ---------------------------------------------------------------------------
__global__ __launch_bounds__(256) void gemm_sm(
    const ushort* __restrict__ A, const ushort* __restrict__ BT,
    const float* __restrict__ g1, const float* __restrict__ b1,
    const float* __restrict__ m1, const float* __restrict__ v1,
    const float* __restrict__ ga, ushort* __restrict__ actT) {
  constexpr int K = EFn, N = Nrows;
  __shared__ ushort sh[16384];
  __shared__ float sScale[128], sShift[128];
  const int tid = threadIdx.x;
  const int wave = tid >> 6, lane = tid & 63;
  const int nbx = gridDim.x;
  const int lid = xcd_lid();
  const int gm = (lid / nbx) * 128, gn = (lid % nbx) * 128;
  const int wr = wave >> 1, wc = wave & 1;

  if (tid < 128) {
    const int row = gm + tid;
    const float sc = g1[row] * rsqrtf(v1[row] + EPSV);
    sScale[tid] = sc;
    sShift[tid] = b1[row] - m1[row] * sc;
  }

  const int c0 = tid, c1 = tid + 256;
  const ushort* gA0 = A + (size_t)(gm + (c0 >> 2)) * K + (c0 & 3) * 8;
  const ushort* gA1 = A + (size_t)(gm + (c1 >> 2)) * K + (c1 & 3) * 8;
  const ushort* gB0 = BT + (size_t)(gn + (c0 >> 2)) * K + (c0 & 3) * 8;
  const ushort* gB1 = BT + (size_t)(gn + (c1 >> 2)) * K + (c1 & 3) * 8;

  f32x4 acc[4][4] = {};
  const int arow = wr * 64 + (lane & 15);
  const int brow = wc * 64 + (lane & 15);
  const int koff = (lane >> 4) * 8;
  const int nk = K >> 5;

#define SM_STAGE(buf, k0)                                    \
  {                                                          \
    load16(gA0 + (k0), &sh[(buf)*8192 + wave * 512]);        \
    load16(gA1 + (k0), &sh[(buf)*8192 + 2048 + wave * 512]); \
    load16(gB0 + (k0), &sh[(buf)*8192 + 4096 + wave * 512]); \
    load16(gB1 + (k0), &sh[(buf)*8192 + 6144 + wave * 512]); \
  }

  SM_STAGE(0, 0);
  __syncthreads();
  for (int t = 0; t < nk; ++t) {
    const int buf = t & 1;
    if (t + 1 < nk) SM_STAGE(buf ^ 1, (t + 1) * 32);
    short8 a[4], b[4];
#pragma unroll
    for (int m = 0; m < 4; ++m)
      a[m] = *reinterpret_cast<const short8*>(
          &sh[buf * 8192 + (arow + m * 16) * 32 + koff]);
#pragma unroll
    for (int n = 0; n < 4; ++n)
      b[n] = *reinterpret_cast<const short8*>(
          &sh[buf * 8192 + 4096 + (brow + n * 16) * 32 + koff]);
#pragma unroll
    for (int m = 0; m < 4; ++m)
#pragma unroll
      for (int n = 0; n < 4; ++n)
        acc[m][n] = __builtin_amdgcn_mfma_f32_16x16x32_bf16(
            a[m], b[n], acc[m][n], 0, 0, 0);
    __syncthreads();
  }
#undef SM_STAGE

  const int l15 = lane & 15, l4 = lane >> 4;
  const int g = (gm >> 6) + wr;
#pragma unroll
  for (int n = 0; n < 4; ++n) {
    const int col = gn + wc * 64 + n * 16 + l15;
    float mx = -1e30f;
#pragma unroll
    for (int m = 0; m < 4; ++m)
#pragma unroll
      for (int j = 0; j < 4; ++j) {
        const int rl = wr * 64 + m * 16 + l4 * 4 + j;
        acc[m][n][j] = acc[m][n][j] * sScale[rl] + sShift[rl];
        mx = fmaxf(mx, acc[m][n][j]);
      }
    mx = fmaxf(mx, __shfl_xor(mx, 16));
    mx = fmaxf(mx, __shfl_xor(mx, 32));
    float sum = 0.f;
#pragma unroll
    for (int m = 0; m < 4; ++m)
#pragma unroll
      for (int j = 0; j < 4; ++j) {
        acc[m][n][j] = expf(acc[m][n][j] - mx);
        sum += acc[m][n][j];
      }
    sum += __shfl_xor(sum, 16);
    sum += __shfl_xor(sum, 32);
    const float sc = ga[(size_t)col * 8 + g] / sum;
#pragma unroll
    for (int m = 0; m < 4; ++m)
#pragma unroll
      for (int j = 0; j < 4; ++j) {
        const int rowg = gm + wr * 64 + m * 16 + l4 * 4 + j;
        actT[(size_t)rowg * N + col] = f2bf(acc[m][n][j] * sc);
      }
  }
}

// ---------------------------------------------------------------------------
__global__ __launch_bounds__(256) void cvt_kernel(const float* __restrict__ in,
                                                  ushort* __restrict__ out,
                                                  int n4) {
  const int i = blockIdx.x * 256 + threadIdx.x;
  if (i >= n4) return;
  const float4 v = reinterpret_cast<const float4*>(in)[i];
  ushort4 o;
  o.x = f2bf(v.x); o.y = f2bf(v.y); o.z = f2bf(v.z); o.w = f2bf(v.w);
  reinterpret_cast<ushort4*>(out)[i] = o;
}

// ---------------------------------------------------------------------------
// transpose + convert: in f32 [R][C] -> out bf16 [C][R]
// ---------------------------------------------------------------------------
__global__ __launch_bounds__(256) void tconv_kernel(const float* __restrict__ in,
                                                    ushort* __restrict__ out,
                                                    int R, int C) {
  __shared__ float t[32][33];
  const int tx = threadIdx.x & 31, ty = threadIdx.x >> 5;
  const int bc = blockIdx.x * 32, br = blockIdx.y * 32;
#pragma unroll
  for (int i = 0; i < 32; i += 8)
    t[ty + i][tx] = in[(size_t)(br + ty + i) * C + bc + tx];
  __syncthreads();
#pragma unroll
  for (int i = 0; i < 32; i += 8)
    out[(size_t)(bc + ty + i) * R + br + tx] = f2bf(t[tx][ty + i]);
}

// ---------------------------------------------------------------------------
// W_ga [1536][8] f32 -> WTga [16][1536] bf16 (rows 8..15 zero)
// ---------------------------------------------------------------------------
__global__ __launch_bounds__(256) void gawt_kernel(const float* __restrict__ in,
                                                   ushort* __restrict__ out) {
  const int k = blockIdx.x * 256 + threadIdx.x;  // 0..1535
#pragma unroll
  for (int g = 0; g < 8; ++g) {
    out[(size_t)g * EFn + k] = f2bf(in[(size_t)k * 8 + g]);
    out[(size_t)(g + 8) * EFn + k] = 0;
  }
}

// ---------------------------------------------------------------------------
// cent_mfma: block per (b,g). part[b*8+g][c=64][f=192], K=1024 over s.
// ---------------------------------------------------------------------------
__global__ __launch_bounds__(256) void cent_mfma(
    const ushort* __restrict__ actT, const ushort* __restrict__ feaT,
    float* __restrict__ part) {
  __shared__ ushort As[2][64 * 64];
  __shared__ ushort Bs[2][192 * 64];
  const int tid = threadIdx.x;
  const int wave = tid >> 6, lane = tid & 63;
  const int b = blockIdx.x >> 3, g = blockIdx.x & 7;
  const size_t colbase = (size_t)b * 1024;
  const int srow = tid >> 2, scp = (tid & 3) * 2;
  const ushort* gA = actT + (size_t)(g * 64 + srow) * Nrows + colbase;
  const ushort* gB0 = feaT + (size_t)(g * 192 + srow) * Nrows + colbase;
  const ushort* gB1 = gB0 + (size_t)64 * Nrows;
  const ushort* gB2 = gB0 + (size_t)128 * Nrows;

  uint4 ra[2], rb0[2], rb1[2], rb2[2];
  f32x4 acc[4][3] = {};
  const int l15 = lane & 15, hi = lane >> 4;
  const int sw = srow & 7;

#define CM_ISSUE(k0)                                                    \
  {                                                                     \
    _Pragma("unroll") for (int i = 0; i < 2; ++i) {                     \
      const int off = (k0) + (scp + i) * 8;                             \
      ra[i] = *reinterpret_cast<const uint4*>(gA + off);                \
      rb0[i] = *reinterpret_cast<const uint4*>(gB0 + off);              \
      rb1[i] = *reinterpret_cast<const uint4*>(gB1 + off);              \
      rb2[i] = *reinterpret_cast<const uint4*>(gB2 + off);              \
    }                                                                   \
  }
#define CM_STASH(buf)                                                   \
  {                                                                     \
    _Pragma("unroll") for (int i = 0; i < 2; ++i) {                     \
      const int c = scp + i;                                            \
      *reinterpret_cast<uint4*>(&As[buf][srow * 64 + ((c ^ sw) * 8)]) = \
          ra[i];                                                        \
      *reinterpret_cast<uint4*>(&Bs[buf][srow * 64 + ((c ^ sw) * 8)]) = \
          rb0[i];                                                       \
      *reinterpret_cast<uint4*>(                                        \
          &Bs[buf][(64 + srow) * 64 + ((c ^ sw) * 8)]) = rb1[i];        \
      *reinterpret_cast<uint4*>(                                        \
          &Bs[buf][(128 + srow) * 64 + ((c ^ sw) * 8)]) = rb2[i];       \
    }                                                                   \
  }

  CM_ISSUE(0);
  CM_STASH(0);
  for (int kk = 0; kk < 16; ++kk) {
    const int buf = kk & 1;
    if (kk < 15) CM_ISSUE((kk + 1) * 64);
    __syncthreads();
#pragma unroll
    for (int ks = 0; ks < 2; ++ks) {
      const int ch = ks * 4 + hi;
      short8 a[4], bb[3];
#pragma unroll
      for (int m = 0; m < 4; ++m) {
        const int r = m * 16 + l15;
        a[m] = *reinterpret_cast<const short8*>(
            &As[buf][r * 64 + ((ch ^ (r & 7)) * 8)]);
      }
#pragma unroll
      for (int nn = 0; nn < 3; ++nn) {
        const int r = wave * 48 + nn * 16 + l15;
        bb[nn] = *reinterpret_cast<const short8*>(
            &Bs[buf][r * 64 + ((ch ^ (r & 7)) * 8)]);
      }
#pragma unroll
      for (int m = 0; m < 4; ++m)
#pragma unroll
        for (int nn = 0; nn < 3; ++nn)
          acc[m][nn] = __builtin_amdgcn_mfma_f32_16x16x32_bf16(
              a[m], bb[nn], acc[m][nn], 0, 0, 0);
    }
    if (kk < 15) CM_STASH(buf ^ 1);
  }
#undef CM_ISSUE
#undef CM_STASH

  float* pb = part + (size_t)blockIdx.x * 12288;
#pragma unroll
  for (int m = 0; m < 4; ++m)
#pragma unroll
    for (int nn = 0; nn < 3; ++nn) {
      const int col = wave * 48 + nn * 16 + l15;
#pragma unroll
      for (int j = 0; j < 4; ++j) {
        const int row = m * 16 + hi * 4 + j;
        pb[row * 192 + col] = acc[m][nn][j];
      }
    }
}

// reduce over g -> cent bf16 [2048][192]
__global__ __launch_bounds__(256) void cent_reduce8(
    const float* __restrict__ part, ushort* __restrict__ cent) {
  const int idx = blockIdx.x * 256 + threadIdx.x;  // < 393216
  const int b = idx / 12288, r = idx % 12288;
  float s = 0.f;
#pragma unroll
  for (int g = 0; g < 8; ++g) s += part[(size_t)(b * 8 + g) * 12288 + r];
  cent[idx] = f2bf(s);
}

// ---------------------------------------------------------------------------
// MFMA attention (verified R3): one wave per 32 q-rows, all-register.
// ---------------------------------------------------------------------------
__global__ __launch_bounds__(256) void attn_mfma(
    const ushort* __restrict__ qb, const ushort* __restrict__ kb,
    const ushort* __restrict__ vtb, ushort* __restrict__ aout) {
  const int wave = threadIdx.x >> 6, lane = threadIdx.x & 63;
  const int wrow = blockIdx.x * 4 + wave;
  const int row0 = wrow * 32;
  const int b = row0 >> 10;
  const int l31 = lane & 31, hi = lane >> 5;

  f32x16 accs0 = 0.f, accs1 = 0.f;
  const ushort* qp = qb + (size_t)(row0 + l31) * 384 + hi * 8;
  const ushort* kp = kb + (size_t)(b * 64 + l31) * 384 + hi * 8;
#pragma unroll 4
  for (int ks = 0; ks < 24; ++ks) {
    const short8 bq = *reinterpret_cast<const short8*>(qp + ks * 16);
    const short8 a0 = *reinterpret_cast<const short8*>(kp + ks * 16);
    const short8 a1 = *reinterpret_cast<const short8*>(kp + 32 * 384 + ks * 16);
    accs0 = __builtin_amdgcn_mfma_f32_32x32x16_bf16(a0, bq, accs0, 0, 0, 0);
    accs1 = __builtin_amdgcn_mfma_f32_32x32x16_bf16(a1, bq, accs1, 0, 0, 0);
  }

  const float alpha = 0.05103103630798287f;
  float p[32];
#pragma unroll
  for (int i = 0; i < 16; ++i) { p[i] = accs0[i]; p[16 + i] = accs1[i]; }
  float mx = p[0];
#pragma unroll
  for (int i = 1; i < 32; ++i) mx = fmaxf(mx, p[i]);
  mx = fmaxf(mx, __shfl_xor(mx, 32));
  float sum = 0.f;
#pragma unroll
  for (int i = 0; i < 32; ++i) {
    p[i] = expf((p[i] - mx) * alpha);
    sum += p[i];
  }
  sum += __shfl_xor(sum, 32);
  const float inv = 1.0f / sum;

  uint pk0[8], pk1[8];
#pragma unroll
  for (int ct = 0; ct < 2; ++ct)
#pragma unroll
    for (int rg = 0; rg < 4; ++rg) {
      pk0[ct * 4 + rg] =
          pack2bf(p[ct * 16 + rg * 4 + 0] * inv, p[ct * 16 + rg * 4 + 1] * inv);
      pk1[ct * 4 + rg] =
          pack2bf(p[ct * 16 + rg * 4 + 2] * inv, p[ct * 16 + rg * 4 + 3] * inv);
    }
  uint ex0[8], ex1[8];
#pragma unroll
  for (int i = 0; i < 8; ++i) {
    ex0[i] = __shfl_xor(pk0[i], 32);
    ex1[i] = __shfl_xor(pk1[i], 32);
  }

  const ushort* vp = vtb + ((size_t)b * 384 + l31) * 64 + hi * 8;
  ushort* orow = aout + (size_t)(row0 + l31) * 384;
  for (int mt = 0; mt < 12; ++mt) {
    f32x16 acco = 0.f;
#pragma unroll
    for (int kc = 0; kc < 4; ++kc) {
      const short8 av = *reinterpret_cast<const short8*>(
          vp + (size_t)mt * 32 * 64 + kc * 16);
      const int base = (kc >> 1) * 4 + (kc & 1) * 2;
      const uint o0 = hi ? pk0[base + 1] : pk0[base];
      const uint o1 = hi ? pk1[base + 1] : pk1[base];
      const uint e0 = hi ? ex0[base + 1] : ex0[base];
      const uint e1 = hi ? ex1[base + 1] : ex1[base];
      uint4 uu;
      uu.x = hi ? e0 : o0;
      uu.y = hi ? e1 : o1;
      uu.z = hi ? o0 : e0;
      uu.w = hi ? o1 : e1;
      const short8 bp = __builtin_bit_cast(short8, uu);
      acco = __builtin_amdgcn_mfma_f32_32x32x16_bf16(av, bp, acco, 0, 0, 0);
    }
#pragma unroll
    for (int rg = 0; rg < 4; ++rg) {
      ushort4 ov;
      ov.x = f2bf(acco[rg * 4 + 0]);
      ov.y = f2bf(acco[rg * 4 + 1]);
      ov.z = f2bf(acco[rg * 4 + 2]);
      ov.w = f2bf(acco[rg * 4 + 3]);
      *reinterpret_cast<ushort4*>(&orow[mt * 32 + rg * 8 + hi * 4]) = ov;
    }
  }
}

// ---------------------------------------------------------------------------
extern "C" void kernel_launch(void* const* d_in, const int* in_sizes, int n_in,
                              void* d_out, int out_size, void* d_ws,
                              size_t ws_size, hipStream_t stream) {
  (void)in_sizes; (void)n_in; (void)out_size; (void)ws_size;
  const float* x      = (const float*)d_in[0];
  const float* W_exp  = (const float*)d_in[1];
  const float* b_exp  = (const float*)d_in[2];
  const float* W_ga   = (const float*)d_in[3];
  const float* b_ga   = (const float*)d_in[4];
  const float* bn1_g  = (const float*)d_in[5];
  const float* bn1_b  = (const float*)d_in[6];
  const float* bn1_m  = (const float*)d_in[7];
  const float* bn1_v  = (const float*)d_in[8];
  const float* cw     = (const float*)d_in[9];
  const float* W_proj = (const float*)d_in[10];
  const float* b_proj = (const float*)d_in[11];
  const float* bn2_g  = (const float*)d_in[12];
  const float* bn2_b  = (const float*)d_in[13];
  const float* bn2_m  = (const float*)d_in[14];
  const float* bn2_v  = (const float*)d_in[15];
  const float* Wq     = (const float*)d_in[16];
  const float* bq     = (const float*)d_in[17];
  const float* Wkv    = (const float*)d_in[18];
  const float* bkv    = (const float*)d_in[19];
  const float* Wp2    = (const float*)d_in[20];
  const float* bp2    = (const float*)d_in[21];
  float* out = (float*)d_out;

  char* ws = (char*)d_ws;
  // region A @0: fea bf16 100.66MB; aout bf16 25.2MB reuse after cent
  ushort* fea  = (ushort*)(ws + 0);
  ushort* aout = (ushort*)(ws + 0);
  // region B @100663296: xb 50.3MB; actT bf16 33.6MB reuse after q GEMM
  ushort* xb   = (ushort*)(ws + 100663296ull);
  ushort* actT = (ushort*)(ws + 100663296ull);
  ushort* q_bf = (ushort*)(ws + 150994944ull);  // 25.2MB
  float*  ga   = (float*)(ws + 176160768ull);   // 1MB
  float*  part = (float*)(ws + 177209344ull);   // 12.6MB
  ushort* cent = (ushort*)(ws + 189792256ull);  // 0.75MB bf16
  ushort* nc   = (ushort*)(ws + 191365120ull);  // 3.1MB bf16
  ushort* k_bf = (ushort*)(ws + 197656576ull);  // 1.5MB
  ushort* vT_bf= (ushort*)(ws + 199229440ull);  // 1.5MB
  ushort* WT1  = (ushort*)(ws + 200802304ull);  // W_exp^T  [1536][768]
  ushort* WT2  = (ushort*)(ws + 203161600ull);  // cw^T     [512][1536]
  ushort* WT3  = (ushort*)(ws + 204734464ull);  // Wq^T     [384][768]
  ushort* WT4  = (ushort*)(ws + 205324288ull);  // Wp2^T    [768][384]
  ushort* WT5  = (ushort*)(ws + 205914112ull);  // W_proj^T [768][192]
  ushort* WT6  = (ushort*)(ws + 206209024ull);  // Wkv^T    [768][768]
  ushort* WTga = (ushort*)(ws + 207388672ull);  // W_ga^T   [16][1536]
  // feaT lives in d_out (exactly 100,663,296 bytes), dead before final GEMM
  ushort* feaT = (ushort*)d_out;

  dim3 blk(256);
  // 1. conversions / weight transposes
  cvt_kernel<<<dim3((Nrows * Dn / 4 + 255) / 256), blk, 0, stream>>>(
      x, xb, Nrows * Dn / 4);
  tconv_kernel<<<dim3(EFn / 32, Dn / 32), blk, 0, stream>>>(W_exp, WT1, Dn, EFn);
  tconv_kernel<<<dim3(512 / 32, EFn / 32), blk, 0, stream>>>(cw, WT2, EFn, 512);
  tconv_kernel<<<dim3(Pn / 32, Dn / 32), blk, 0, stream>>>(Wq, WT3, Dn, Pn);
  tconv_kernel<<<dim3(Dn / 32, Pn / 32), blk, 0, stream>>>(Wp2, WT4, Pn, Dn);
  tconv_kernel<<<dim3(Dn / 32, GFSn / 32), blk, 0, stream>>>(W_proj, WT5, GFSn, Dn);
  tconv_kernel<<<dim3(Dn / 32, Dn / 32), blk, 0, stream>>>(Wkv, WT6, Dn, Dn);
  gawt_kernel<<<dim3(EFn / 256), blk, 0, stream>>>(W_ga, WTga);
  // 2. fea = bf16(x @ W_exp + b_exp); fused feaT write
  gemm_bf16<1, 1><<<dim3(EFn / 128, Nrows / 128), blk, 0, stream>>>(
      xb, WT1, b_exp, fea, feaT, Nrows, EFn, Dn,
      nullptr, nullptr, nullptr, nullptr, nullptr, nullptr);
  // 3. q = bf16(x @ Wq + bq)   (last consumer of xb)
  gemm_bf16<1, 0><<<dim3(Pn / 128, Nrows / 128), blk, 0, stream>>>(
      xb, WT3, bq, q_bf, nullptr, Nrows, Pn, Dn,
      nullptr, nullptr, nullptr, nullptr, nullptr, nullptr);
  // 4. ga = sigmoid(fea @ W_ga + b_ga)  (MFMA)
  gemm_ga<<<dim3(Nrows / 128), blk, 0, stream>>>(fea, WTga, b_ga, ga);
  // 5. actT = softmax-gemm(cw^T @ fea^T)
  gemm_sm<<<dim3(Nrows / 128, 512 / 128), blk, 0, stream>>>(
      WT2, fea, bn1_g, bn1_b, bn1_m, bn1_v, ga, actT);
  // 6. cent = sum_g actT_g @ feaT_g^T  -> bf16
  cent_mfma<<<dim3(Bn * Gn), blk, 0, stream>>>(actT, feaT, part);
  cent_reduce8<<<dim3(393216 / 256), blk, 0, stream>>>(part, cent);
  // 7. nc = bf16(BN2(cent @ W_proj + b_proj))   (MFMA, M=2048,N=768,K=192)
  gemm_bf16<2, 0><<<dim3(Dn / 128, 2048 / 128), blk, 0, stream>>>(
      cent, WT5, b_proj, nc, nullptr, 2048, Dn, GFSn,
      bn2_g, bn2_b, bn2_m, bn2_v, nullptr, nullptr);
  // 8. kv = nc @ Wkv + bkv -> k_bf, vT_bf   (MFMA, M=2048,N=768,K=768)
  gemm_bf16<3, 0><<<dim3(Dn / 128, 2048 / 128), blk, 0, stream>>>(
      nc, WT6, bkv, nullptr, nullptr, 2048, Dn, Dn,
      nullptr, nullptr, nullptr, nullptr, k_bf, vT_bf);
  // 9. attention
  attn_mfma<<<dim3(Nrows / 128), blk, 0, stream>>>(q_bf, k_bf, vT_bf, aout);
  // 10. out = aout @ Wp2 + bp2  (overwrites feaT scratch)
  gemm_bf16<0, 0><<<dim3(Dn / 128, Nrows / 128), blk, 0, stream>>>(
      aout, WT4, bp2, out, nullptr, Nrows, Dn, Pn,
      nullptr, nullptr, nullptr, nullptr, nullptr, nullptr);
}

// Round 7
// 482.765 us; speedup vs baseline: 1.5957x; 1.0609x over previous
//
#include <hip/hip_runtime.h>
#include <hip/hip_bf16.h>

#define EPSV 1e-5f

namespace {
constexpr int Bn = 32, Sn = 1024, Dn = 768, Gn = 8, Cn = 64, Pn = 384;
constexpr int EFn = 1536, GFSn = 192, Nrows = Bn * Sn;  // 32768
}

typedef __attribute__((ext_vector_type(8))) short short8;
typedef __attribute__((ext_vector_type(4))) float f32x4;
typedef __attribute__((ext_vector_type(16))) float f32x16;

__device__ __forceinline__ ushort f2bf(float f) {
  uint u = __builtin_bit_cast(uint, f);
  uint r = (u + 0x7fffu + ((u >> 16) & 1u)) >> 16;
  return (ushort)r;
}
__device__ __forceinline__ uint pack2bf(float lo, float hi) {
  return (uint)f2bf(lo) | ((uint)f2bf(hi) << 16);
}
__device__ __forceinline__ float bf2f(ushort h) {
  return __builtin_bit_cast(float, (uint)h << 16);
}
__device__ __forceinline__ void load16(const ushort* g, ushort* l) {
  __builtin_amdgcn_global_load_lds(
      (const __attribute__((address_space(1))) void*)g,
      (__attribute__((address_space(3))) void*)l, 16, 0, 0);
}
// T1 bijective XCD swizzle (m204)
__device__ __forceinline__ int xcd_lid() {
  const int nbx = gridDim.x;
  const int nwg = nbx * gridDim.y;
  const int orig = blockIdx.y * nbx + blockIdx.x;
  const int xq = nwg >> 3, xr = nwg & 7;
  const int xcd = orig & 7, xi = orig >> 3;
  return (xcd < xr ? xcd * (xq + 1) : xr * (xq + 1) + (xcd - xr) * xq) + xi;
}

// ---------------------------------------------------------------------------
// bf16 MFMA GEMM: 128x128 tile, BK=32, 4 waves (2x2), counted-vmcnt pipeline
// (tile t+1's 4 global_load_lds stay in flight across the barrier; only tile
// t's loads are waited via vmcnt(4) — removes the per-K-step HBM-latency
// drain of __syncthreads' vmcnt(0)). Two raw s_barriers per K-step:
//   B1 (after waitcnt): tile-t LDS valid for all waves
//   B2 (after MFMA):    all reads of buf[t&1] done before next STAGE writes it
// Epilogue MODE: 0 f32 out; 1 bf16 out (TRANS=1: +C^T to Ct); 2 bf16+BN2;
// 3 kv split.
// ---------------------------------------------------------------------------
template <int MODE, int TRANS>
__global__ __launch_bounds__(256) void gemm_bf16(
    const ushort* __restrict__ A, const ushort* __restrict__ BT,
    const float* __restrict__ bias, void* __restrict__ Cout,
    ushort* __restrict__ Ct, int M, int N, int K,
    const float* __restrict__ g2, const float* __restrict__ b2,
    const float* __restrict__ m2, const float* __restrict__ v2,
    ushort* __restrict__ kq, ushort* __restrict__ vt) {
  __shared__ ushort sh[16384];  // 2 x (As 4096 | Bs 4096); epilogue staging
  const int tid = threadIdx.x;
  const int wave = tid >> 6, lane = tid & 63;
  const int nbx = gridDim.x;
  const int lid = xcd_lid();
  const int gm = (lid / nbx) * 128, gn = (lid % nbx) * 128;
  const int wr = wave >> 1, wc = wave & 1;

  const int c0 = tid, c1 = tid + 256;
  const ushort* gA0 = A + (size_t)(gm + (c0 >> 2)) * K + (c0 & 3) * 8;
  const ushort* gA1 = A + (size_t)(gm + (c1 >> 2)) * K + (c1 & 3) * 8;
  const ushort* gB0 = BT + (size_t)(gn + (c0 >> 2)) * K + (c0 & 3) * 8;
  const ushort* gB1 = BT + (size_t)(gn + (c1 >> 2)) * K + (c1 & 3) * 8;

  f32x4 acc[4][4] = {};
  const int arow = wr * 64 + (lane & 15);
  const int brow = wc * 64 + (lane & 15);
  const int koff = (lane >> 4) * 8;
  const int nk = K >> 5;

#define GB_STAGE(buf, k0)                                    \
  {                                                          \
    load16(gA0 + (k0), &sh[(buf)*8192 + wave * 512]);        \
    load16(gA1 + (k0), &sh[(buf)*8192 + 2048 + wave * 512]); \
    load16(gB0 + (k0), &sh[(buf)*8192 + 4096 + wave * 512]); \
    load16(gB1 + (k0), &sh[(buf)*8192 + 6144 + wave * 512]); \
  }

  GB_STAGE(0, 0);
  for (int t = 0; t < nk; ++t) {
    const int buf = t & 1;
    if (t + 1 < nk) {
      GB_STAGE(buf ^ 1, (t + 1) * 32);
      __builtin_amdgcn_sched_barrier(0);
      asm volatile("s_waitcnt vmcnt(4)" ::: "memory");
    } else {
      asm volatile("s_waitcnt vmcnt(0)" ::: "memory");
    }
    __builtin_amdgcn_s_barrier();       // B1: tile-t LDS valid
    __builtin_amdgcn_sched_barrier(0);  // pin ds_reads below B1
    short8 a[4], b[4];
#pragma unroll
    for (int m = 0; m < 4; ++m)
      a[m] = *reinterpret_cast<const short8*>(
          &sh[buf * 8192 + (arow + m * 16) * 32 + koff]);
#pragma unroll
    for (int n = 0; n < 4; ++n)
      b[n] = *reinterpret_cast<const short8*>(
          &sh[buf * 8192 + 4096 + (brow + n * 16) * 32 + koff]);
#pragma unroll
    for (int m = 0; m < 4; ++m)
#pragma unroll
      for (int n = 0; n < 4; ++n)
        acc[m][n] = __builtin_amdgcn_mfma_f32_16x16x32_bf16(
            a[m], b[n], acc[m][n], 0, 0, 0);
    __builtin_amdgcn_s_barrier();       // B2: reads of buf[t&1] done
    __builtin_amdgcn_sched_barrier(0);
  }
#undef GB_STAGE

  // epilogue: C/D layout col=lane&15, row=(lane>>4)*4+j
  const int crow0 = gm + wr * 64 + (lane >> 4) * 4;
  const int ccol0 = gn + wc * 64 + (lane & 15);
  float sc_[4][4], sf_[4][4];
  if (MODE == 2) {
#pragma unroll
    for (int m = 0; m < 4; ++m)
#pragma unroll
      for (int j = 0; j < 4; ++j) {
        const int c = (crow0 + m * 16 + j) & 63;
        const float s = g2[c] * rsqrtf(v2[c] + EPSV);
        sc_[m][j] = s;
        sf_[m][j] = b2[c] - m2[c] * s;
      }
  }
  alignas(8) ushort cb[4][4][4];
#pragma unroll
  for (int m = 0; m < 4; ++m)
#pragma unroll
    for (int n = 0; n < 4; ++n) {
      const int col = ccol0 + n * 16;
      const float bv = bias ? bias[col] : 0.f;
#pragma unroll
      for (int j = 0; j < 4; ++j) {
        const int row = crow0 + m * 16 + j;
        float v = acc[m][n][j] + bv;
        if (MODE == 0) {
          ((float*)Cout)[(size_t)row * N + col] = v;
        } else if (MODE == 1) {
          const ushort h = f2bf(v);
          ((ushort*)Cout)[(size_t)row * N + col] = h;
          if (TRANS) cb[m][n][j] = h;
        } else if (MODE == 2) {
          v = v * sc_[m][j] + sf_[m][j];
          ((ushort*)Cout)[(size_t)row * N + col] = f2bf(v);
        } else {  // MODE 3: kv split
          const ushort h = f2bf(v);
          if (col < 384) {
            kq[(size_t)row * 384 + col] = h;
          } else {
            vt[(size_t)(row >> 6) * 24576 + (size_t)(col - 384) * 64 +
               (row & 63)] = h;
          }
        }
      }
    }

  if (TRANS) {
    // restage transposed tile through LDS (stride 136), coalesced 16B stores
    const int l15 = lane & 15, l4 = lane >> 4;
#pragma unroll
    for (int p = 0; p < 2; ++p) {
      __syncthreads();
      if (wc == p) {
#pragma unroll
        for (int n = 0; n < 4; ++n) {
          const int cl = n * 16 + l15;
#pragma unroll
          for (int m = 0; m < 4; ++m) {
            const int r = wr * 64 + m * 16 + l4 * 4;
            *reinterpret_cast<ushort4*>(&sh[cl * 136 + r]) =
                *reinterpret_cast<const ushort4*>(&cb[m][n][0]);
          }
        }
      }
      __syncthreads();
      const int cl = tid >> 2, seg = tid & 3;
      const ushort* src = &sh[cl * 136 + seg * 32];
      ushort* dst = Ct + (size_t)(gn + p * 64 + cl) * M + gm + seg * 32;
      *reinterpret_cast<uint4*>(dst) = *reinterpret_cast<const uint4*>(src);
      *reinterpret_cast<uint4*>(dst + 8) =
          *reinterpret_cast<const uint4*>(src + 8);
      *reinterpret_cast<uint4*>(dst + 16) =
          *reinterpret_cast<const uint4*>(src + 16);
      *reinterpret_cast<uint4*>(dst + 24) =
          *reinterpret_cast<const uint4*>(src + 24);
    }
  }
}

// ---------------------------------------------------------------------------
// gemm_ga: ga[32768][8] = sigmoid(fea @ W_ga + b_ga) via MFMA, counted vmcnt.
// wave0 stages B (3 loads/step), others 2; uniform vmcnt(2) is correct for
// both (drains all old loads; over-waits 1 new load on wave0 only).
// ---------------------------------------------------------------------------
__global__ __launch_bounds__(256) void gemm_ga(
    const ushort* __restrict__ fea, const ushort* __restrict__ WTga,
    const float* __restrict__ b_ga, float* __restrict__ ga) {
  constexpr int K = EFn;
  __shared__ ushort sh[9216];  // 2 x (As 4096 | Bs 512)
  const int tid = threadIdx.x;
  const int wave = tid >> 6, lane = tid & 63;
  const int gm = blockIdx.x * 128;

  const int c0 = tid, c1 = tid + 256;
  const ushort* gA0 = fea + (size_t)(gm + (c0 >> 2)) * K + (c0 & 3) * 8;
  const ushort* gA1 = fea + (size_t)(gm + (c1 >> 2)) * K + (c1 & 3) * 8;
  const ushort* gB = WTga + (size_t)(lane >> 2) * K + (lane & 3) * 8;

  f32x4 acc[2] = {};
  const int l15 = lane & 15, l4 = lane >> 4;
  const int koff = l4 * 8;

#define GA_STAGE(buf, k0)                                     \
  {                                                           \
    load16(gA0 + (k0), &sh[(buf)*4608 + wave * 512]);         \
    load16(gA1 + (k0), &sh[(buf)*4608 + 2048 + wave * 512]);  \
    if (wave == 0) load16(gB + (k0), &sh[(buf)*4608 + 4096]); \
  }

  GA_STAGE(0, 0);
  for (int t = 0; t < K / 32; ++t) {
    const int buf = t & 1;
    if (t + 1 < K / 32) {
      GA_STAGE(buf ^ 1, (t + 1) * 32);
      __builtin_amdgcn_sched_barrier(0);
      asm volatile("s_waitcnt vmcnt(2)" ::: "memory");
    } else {
      asm volatile("s_waitcnt vmcnt(0)" ::: "memory");
    }
    __builtin_amdgcn_s_barrier();
    __builtin_amdgcn_sched_barrier(0);
    const short8 b = *reinterpret_cast<const short8*>(
        &sh[buf * 4608 + 4096 + l15 * 32 + koff]);
    short8 a[2];
#pragma unroll
    for (int mi = 0; mi < 2; ++mi)
      a[mi] = *reinterpret_cast<const short8*>(
          &sh[buf * 4608 + (wave * 32 + mi * 16 + l15) * 32 + koff]);
#pragma unroll
    for (int mi = 0; mi < 2; ++mi)
      acc[mi] =
          __builtin_amdgcn_mfma_f32_16x16x32_bf16(a[mi], b, acc[mi], 0, 0, 0);
    __builtin_amdgcn_s_barrier();
    __builtin_amdgcn_sched_barrier(0);
  }
#undef GA_STAGE

  if (l15 < 8) {
    const float bv = b_ga[l15];
#pragma unroll
    for (int mi = 0; mi < 2; ++mi)
#pragma unroll
      for (int j = 0; j < 4; ++j) {
        const int row = gm + wave * 32 + mi * 16 + l4 * 4 + j;
        const float v = acc[mi][j] + bv;
        ga[(size_t)row * 8 + l15] = 1.0f / (1.0f + expf(-v));
      }
  }
}

// ---------------------------------------------------------------------------
// gemm_sm: actT[512][32768] = softmax-epilogue( WT2 @ fea^T ).
// Counted-vmcnt pipeline; gm-FASTEST XCD mapping so the 4 blocks sharing a
// fea panel land in one XCD chunk (fea fetched ~once from HBM, not 4x).
// ---------------------------------------------------------------------------
__global__ __launch_bounds__(256) void gemm_sm(
    const ushort* __restrict__ A, const ushort* __restrict__ BT,
    const float* __restrict__ g1, const float* __restrict__ b1,
    const float* __restrict__ m1, const float* __restrict__ v1,
    const float* __restrict__ ga, ushort* __restrict__ actT) {
  constexpr int K = EFn, N = Nrows;
  __shared__ ushort sh[16384];
  __shared__ float sScale[128], sShift[128];
  const int tid = threadIdx.x;
  const int wave = tid >> 6, lane = tid & 63;
  const int lid = xcd_lid();           // 0..1023
  const int gm = (lid & 3) * 128;      // gm fastest within XCD chunk
  const int gn = (lid >> 2) * 128;
  const int wr = wave >> 1, wc = wave & 1;

  if (tid < 128) {
    const int row = gm + tid;
    const float sc = g1[row] * rsqrtf(v1[row] + EPSV);
    sScale[tid] = sc;
    sShift[tid] = b1[row] - m1[row] * sc;
  }

  const int c0 = tid, c1 = tid + 256;
  const ushort* gA0 = A + (size_t)(gm + (c0 >> 2)) * K + (c0 & 3) * 8;
  const ushort* gA1 = A + (size_t)(gm + (c1 >> 2)) * K + (c1 & 3) * 8;
  const ushort* gB0 = BT + (size_t)(gn + (c0 >> 2)) * K + (c0 & 3) * 8;
  const ushort* gB1 = BT + (size_t)(gn + (c1 >> 2)) * K + (c1 & 3) * 8;

  f32x4 acc[4][4] = {};
  const int arow = wr * 64 + (lane & 15);
  const int brow = wc * 64 + (lane & 15);
  const int koff = (lane >> 4) * 8;
  const int nk = K >> 5;

#define SM_STAGE(buf, k0)                                    \
  {                                                          \
    load16(gA0 + (k0), &sh[(buf)*8192 + wave * 512]);        \
    load16(gA1 + (k0), &sh[(buf)*8192 + 2048 + wave * 512]); \
    load16(gB0 + (k0), &sh[(buf)*8192 + 4096 + wave * 512]); \
    load16(gB1 + (k0), &sh[(buf)*8192 + 6144 + wave * 512]); \
  }

  SM_STAGE(0, 0);
  for (int t = 0; t < nk; ++t) {
    const int buf = t & 1;
    if (t + 1 < nk) {
      SM_STAGE(buf ^ 1, (t + 1) * 32);
      __builtin_amdgcn_sched_barrier(0);
      asm volatile("s_waitcnt vmcnt(4)" ::: "memory");
    } else {
      asm volatile("s_waitcnt vmcnt(0)" ::: "memory");
    }
    __builtin_amdgcn_s_barrier();
    __builtin_amdgcn_sched_barrier(0);
    short8 a[4], b[4];
#pragma unroll
    for (int m = 0; m < 4; ++m)
      a[m] = *reinterpret_cast<const short8*>(
          &sh[buf * 8192 + (arow + m * 16) * 32 + koff]);
#pragma unroll
    for (int n = 0; n < 4; ++n)
      b[n] = *reinterpret_cast<const short8*>(
          &sh[buf * 8192 + 4096 + (brow + n * 16) * 32 + koff]);
#pragma unroll
    for (int m = 0; m < 4; ++m)
#pragma unroll
      for (int n = 0; n < 4; ++n)
        acc[m][n] = __builtin_amdgcn_mfma_f32_16x16x32_bf16(
            a[m], b[n], acc[m][n], 0, 0, 0);
    __builtin_amdgcn_s_barrier();
    __builtin_amdgcn_sched_barrier(0);
  }
#undef SM_STAGE

  const int l15 = lane & 15, l4 = lane >> 4;
  const int g = (gm >> 6) + wr;
#pragma unroll
  for (int n = 0; n < 4; ++n) {
    const int col = gn + wc * 64 + n * 16 + l15;
    float mx = -1e30f;
#pragma unroll
    for (int m = 0; m < 4; ++m)
#pragma unroll
      for (int j = 0; j < 4; ++j) {
        const int rl = wr * 64 + m * 16 + l4 * 4 + j;
        acc[m][n][j] = acc[m][n][j] * sScale[rl] + sShift[rl];
        mx = fmaxf(mx, acc[m][n][j]);
      }
    mx = fmaxf(mx, __shfl_xor(mx, 16));
    mx = fmaxf(mx, __shfl_xor(mx, 32));
    float sum = 0.f;
#pragma unroll
    for (int m = 0; m < 4; ++m)
#pragma unroll
      for (int j = 0; j < 4; ++j) {
        acc[m][n][j] = expf(acc[m][n][j] - mx);
        sum += acc[m][n][j];
      }
    sum += __shfl_xor(sum, 16);
    sum += __shfl_xor(sum, 32);
    const float sc = ga[(size_t)col * 8 + g] / sum;
#pragma unroll
    for (int m = 0; m < 4; ++m)
#pragma unroll
      for (int j = 0; j < 4; ++j) {
        const int rowg = gm + wr * 64 + m * 16 + l4 * 4 + j;
        actT[(size_t)rowg * N + col] = f2bf(acc[m][n][j] * sc);
      }
  }
}

// ---------------------------------------------------------------------------
__global__ __launch_bounds__(256) void cvt_kernel(const float* __restrict__ in,
                                                  ushort* __restrict__ out,
                                                  int n4) {
  const int i = blockIdx.x * 256 + threadIdx.x;
  if (i >= n4) return;
  const float4 v = reinterpret_cast<const float4*>(in)[i];
  ushort4 o;
  o.x = f2bf(v.x); o.y = f2bf(v.y); o.z = f2bf(v.z); o.w = f2bf(v.w);
  reinterpret_cast<ushort4*>(out)[i] = o;
}

// ---------------------------------------------------------------------------
// transpose + convert: in f32 [R][C] -> out bf16 [C][R]
// ---------------------------------------------------------------------------
__global__ __launch_bounds__(256) void tconv_kernel(const float* __restrict__ in,
                                                    ushort* __restrict__ out,
                                                    int R, int C) {
  __shared__ float t[32][33];
  const int tx = threadIdx.x & 31, ty = threadIdx.x >> 5;
  const int bc = blockIdx.x * 32, br = blockIdx.y * 32;
#pragma unroll
  for (int i = 0; i < 32; i += 8)
    t[ty + i][tx] = in[(size_t)(br + ty + i) * C + bc + tx];
  __syncthreads();
#pragma unroll
  for (int i = 0; i < 32; i += 8)
    out[(size_t)(bc + ty + i) * R + br + tx] = f2bf(t[tx][ty + i]);
}

// ---------------------------------------------------------------------------
// W_ga [1536][8] f32 -> WTga [16][1536] bf16 (rows 8..15 zero)
// ---------------------------------------------------------------------------
__global__ __launch_bounds__(256) void gawt_kernel(const float* __restrict__ in,
                                                   ushort* __restrict__ out) {
  const int k = blockIdx.x * 256 + threadIdx.x;  // 0..1535
#pragma unroll
  for (int g = 0; g < 8; ++g) {
    out[(size_t)g * EFn + k] = f2bf(in[(size_t)k * 8 + g]);
    out[(size_t)(g + 8) * EFn + k] = 0;
  }
}

// ---------------------------------------------------------------------------
// cent_mfma: block per (b,g,ch) — s split in 2 chunks of 512 for occupancy
// (512 blocks = 2/CU). part[bid][c=64][f=192]. ISSUE placed AFTER the
// barrier so __syncthreads' vmcnt(0) drain never waits on just-issued loads.
// ---------------------------------------------------------------------------
__global__ __launch_bounds__(256) void cent_mfma(
    const ushort* __restrict__ actT, const ushort* __restrict__ feaT,
    float* __restrict__ part) {
  __shared__ ushort As[2][64 * 64];
  __shared__ ushort Bs[2][192 * 64];
  const int tid = threadIdx.x;
  const int wave = tid >> 6, lane = tid & 63;
  const int b = blockIdx.x >> 4;
  const int g = (blockIdx.x >> 1) & 7;
  const int ch = blockIdx.x & 1;
  const size_t colbase = (size_t)b * 1024 + ch * 512;
  const int srow = tid >> 2, scp = (tid & 3) * 2;
  const ushort* gA = actT + (size_t)(g * 64 + srow) * Nrows + colbase;
  const ushort* gB0 = feaT + (size_t)(g * 192 + srow) * Nrows + colbase;
  const ushort* gB1 = gB0 + (size_t)64 * Nrows;
  const ushort* gB2 = gB0 + (size_t)128 * Nrows;

  uint4 ra[2], rb0[2], rb1[2], rb2[2];
  f32x4 acc[4][3] = {};
  const int l15 = lane & 15, hi = lane >> 4;
  const int sw = srow & 7;

#define CM_ISSUE(k0)                                                    \
  {                                                                     \
    _Pragma("unroll") for (int i = 0; i < 2; ++i) {                     \
      const int off = (k0) + (scp + i) * 8;                             \
      ra[i] = *reinterpret_cast<const uint4*>(gA + off);                \
      rb0[i] = *reinterpret_cast<const uint4*>(gB0 + off);              \
      rb1[i] = *reinterpret_cast<const uint4*>(gB1 + off);              \
      rb2[i] = *reinterpret_cast<const uint4*>(gB2 + off);              \
    }                                                                   \
  }
#define CM_STASH(buf)                                                   \
  {                                                                     \
    _Pragma("unroll") for (int i = 0; i < 2; ++i) {                     \
      const int c = scp + i;                                            \
      *reinterpret_cast<uint4*>(&As[buf][srow * 64 + ((c ^ sw) * 8)]) = \
          ra[i];                                                        \
      *reinterpret_cast<uint4*>(&Bs[buf][srow * 64 + ((c ^ sw) * 8)]) = \
          rb0[i];                                                       \
      *reinterpret_cast<uint4*>(                                        \
          &Bs[buf][(64 + srow) * 64 + ((c ^ sw) * 8)]) = rb1[i];        \
      *reinterpret_cast<uint4*>(                                        \
          &Bs[buf][(128 + srow) * 64 + ((c ^ sw) * 8)]) = rb2[i];       \
    }                                                                   \
  }

  CM_ISSUE(0);
  CM_STASH(0);
  for (int kk = 0; kk < 8; ++kk) {
    const int buf = kk & 1;
    __syncthreads();
    if (kk < 7) CM_ISSUE((kk + 1) * 64);
#pragma unroll
    for (int ks = 0; ks < 2; ++ks) {
      const int chh = ks * 4 + hi;
      short8 a[4], bb[3];
#pragma unroll
      for (int m = 0; m < 4; ++m) {
        const int r = m * 16 + l15;
        a[m] = *reinterpret_cast<const short8*>(
            &As[buf][r * 64 + ((chh ^ (r & 7)) * 8)]);
      }
#pragma unroll
      for (int nn = 0; nn < 3; ++nn) {
        const int r = wave * 48 + nn * 16 + l15;
        bb[nn] = *reinterpret_cast<const short8*>(
            &Bs[buf][r * 64 + ((chh ^ (r & 7)) * 8)]);
      }
#pragma unroll
      for (int m = 0; m < 4; ++m)
#pragma unroll
        for (int nn = 0; nn < 3; ++nn)
          acc[m][nn] = __builtin_amdgcn_mfma_f32_16x16x32_bf16(
              a[m], bb[nn], acc[m][nn], 0, 0, 0);
    }
    if (kk < 7) CM_STASH(buf ^ 1);
  }
#undef CM_ISSUE
#undef CM_STASH

  float* pb = part + (size_t)blockIdx.x * 12288;
#pragma unroll
  for (int m = 0; m < 4; ++m)
#pragma unroll
    for (int nn = 0; nn < 3; ++nn) {
      const int col = wave * 48 + nn * 16 + l15;
#pragma unroll
      for (int j = 0; j < 4; ++j) {
        const int row = m * 16 + hi * 4 + j;
        pb[row * 192 + col] = acc[m][nn][j];
      }
    }
}

// reduce over (g,ch) -> cent bf16 [2048][192]
__global__ __launch_bounds__(256) void cent_reduce8(
    const float* __restrict__ part, ushort* __restrict__ cent) {
  const int idx = blockIdx.x * 256 + threadIdx.x;  // < 393216
  const int b = idx / 12288, r = idx % 12288;
  float s = 0.f;
#pragma unroll
  for (int j = 0; j < 16; ++j) s += part[(size_t)(b * 16 + j) * 12288 + r];
  cent[idx] = f2bf(s);
}

// ---------------------------------------------------------------------------
// MFMA attention (verified R3): one wave per 32 q-rows, all-register.
// ---------------------------------------------------------------------------
__global__ __launch_bounds__(256) void attn_mfma(
    const ushort* __restrict__ qb, const ushort* __restrict__ kb,
    const ushort* __restrict__ vtb, ushort* __restrict__ aout) {
  const int wave = threadIdx.x >> 6, lane = threadIdx.x & 63;
  const int wrow = blockIdx.x * 4 + wave;
  const int row0 = wrow * 32;
  const int b = row0 >> 10;
  const int l31 = lane & 31, hi = lane >> 5;

  f32x16 accs0 = 0.f, accs1 = 0.f;
  const ushort* qp = qb + (size_t)(row0 + l31) * 384 + hi * 8;
  const ushort* kp = kb + (size_t)(b * 64 + l31) * 384 + hi * 8;
#pragma unroll 4
  for (int ks = 0; ks < 24; ++ks) {
    const short8 bq = *reinterpret_cast<const short8*>(qp + ks * 16);
    const short8 a0 = *reinterpret_cast<const short8*>(kp + ks * 16);
    const short8 a1 = *reinterpret_cast<const short8*>(kp + 32 * 384 + ks * 16);
    accs0 = __builtin_amdgcn_mfma_f32_32x32x16_bf16(a0, bq, accs0, 0, 0, 0);
    accs1 = __builtin_amdgcn_mfma_f32_32x32x16_bf16(a1, bq, accs1, 0, 0, 0);
  }

  const float alpha = 0.05103103630798287f;
  float p[32];
#pragma unroll
  for (int i = 0; i < 16; ++i) { p[i] = accs0[i]; p[16 + i] = accs1[i]; }
  float mx = p[0];
#pragma unroll
  for (int i = 1; i < 32; ++i) mx = fmaxf(mx, p[i]);
  mx = fmaxf(mx, __shfl_xor(mx, 32));
  float sum = 0.f;
#pragma unroll
  for (int i = 0; i < 32; ++i) {
    p[i] = expf((p[i] - mx) * alpha);
    sum += p[i];
  }
  sum += __shfl_xor(sum, 32);
  const float inv = 1.0f / sum;

  uint pk0[8], pk1[8];
#pragma unroll
  for (int ct = 0; ct < 2; ++ct)
#pragma unroll
    for (int rg = 0; rg < 4; ++rg) {
      pk0[ct * 4 + rg] =
          pack2bf(p[ct * 16 + rg * 4 + 0] * inv, p[ct * 16 + rg * 4 + 1] * inv);
      pk1[ct * 4 + rg] =
          pack2bf(p[ct * 16 + rg * 4 + 2] * inv, p[ct * 16 + rg * 4 + 3] * inv);
    }
  uint ex0[8], ex1[8];
#pragma unroll
  for (int i = 0; i < 8; ++i) {
    ex0[i] = __shfl_xor(pk0[i], 32);
    ex1[i] = __shfl_xor(pk1[i], 32);
  }

  const ushort* vp = vtb + ((size_t)b * 384 + l31) * 64 + hi * 8;
  ushort* orow = aout + (size_t)(row0 + l31) * 384;
  for (int mt = 0; mt < 12; ++mt) {
    f32x16 acco = 0.f;
#pragma unroll
    for (int kc = 0; kc < 4; ++kc) {
      const short8 av = *reinterpret_cast<const short8*>(
          vp + (size_t)mt * 32 * 64 + kc * 16);
      const int base = (kc >> 1) * 4 + (kc & 1) * 2;
      const uint o0 = hi ? pk0[base + 1] : pk0[base];
      const uint o1 = hi ? pk1[base + 1] : pk1[base];
      const uint e0 = hi ? ex0[base + 1] : ex0[base];
      const uint e1 = hi ? ex1[base + 1] : ex1[base];
      uint4 uu;
      uu.x = hi ? e0 : o0;
      uu.y = hi ? e1 : o1;
      uu.z = hi ? o0 : e0;
      uu.w = hi ? o1 : e1;
      const short8 bp = __builtin_bit_cast(short8, uu);
      acco = __builtin_amdgcn_mfma_f32_32x32x16_bf16(av, bp, acco, 0, 0, 0);
    }
#pragma unroll
    for (int rg = 0; rg < 4; ++rg) {
      ushort4 ov;
      ov.x = f2bf(acco[rg * 4 + 0]);
      ov.y = f2bf(acco[rg * 4 + 1]);
      ov.z = f2bf(acco[rg * 4 + 2]);
      ov.w = f2bf(acco[rg * 4 + 3]);
      *reinterpret_cast<ushort4*>(&orow[mt * 32 + rg * 8 + hi * 4]) = ov;
    }
  }
}

// ---------------------------------------------------------------------------
extern "C" void kernel_launch(void* const* d_in, const int* in_sizes, int n_in,
                              void* d_out, int out_size, void* d_ws,
                              size_t ws_size, hipStream_t stream) {
  (void)in_sizes; (void)n_in; (void)out_size; (void)ws_size;
  const float* x      = (const float*)d_in[0];
  const float* W_exp  = (const float*)d_in[1];
  const float* b_exp  = (const float*)d_in[2];
  const float* W_ga   = (const float*)d_in[3];
  const float* b_ga   = (const float*)d_in[4];
  const float* bn1_g  = (const float*)d_in[5];
  const float* bn1_b  = (const float*)d_in[6];
  const float* bn1_m  = (const float*)d_in[7];
  const float* bn1_v  = (const float*)d_in[8];
  const float* cw     = (const float*)d_in[9];
  const float* W_proj = (const float*)d_in[10];
  const float* b_proj = (const float*)d_in[11];
  const float* bn2_g  = (const float*)d_in[12];
  const float* bn2_b  = (const float*)d_in[13];
  const float* bn2_m  = (const float*)d_in[14];
  const float* bn2_v  = (const float*)d_in[15];
  const float* Wq     = (const float*)d_in[16];
  const float* bq     = (const float*)d_in[17];
  const float* Wkv    = (const float*)d_in[18];
  const float* bkv    = (const float*)d_in[19];
  const float* Wp2    = (const float*)d_in[20];
  const float* bp2    = (const float*)d_in[21];
  float* out = (float*)d_out;

  char* ws = (char*)d_ws;
  // region A @0: fea bf16 100.66MB; aout bf16 25.2MB reuse after cent
  ushort* fea  = (ushort*)(ws + 0);
  ushort* aout = (ushort*)(ws + 0);
  // region B: xb 50.3MB; actT bf16 33.6MB reuse after q GEMM
  ushort* xb   = (ushort*)(ws + 100663296ull);
  ushort* actT = (ushort*)(ws + 100663296ull);
  ushort* q_bf = (ushort*)(ws + 150994944ull);  // 25.2MB
  float*  ga   = (float*)(ws + 176160768ull);   // 1MB
  float*  part = (float*)(ws + 177209344ull);   // 25.2MB (512 x 12288 f32)
  ushort* WT1  = (ushort*)(ws + 202375168ull);  // W_exp^T  [1536][768]
  ushort* WT2  = (ushort*)(ws + 204734464ull);  // cw^T     [512][1536]
  ushort* WT3  = (ushort*)(ws + 206307328ull);  // Wq^T     [384][768]
  ushort* WT4  = (ushort*)(ws + 206897152ull);  // Wp2^T    [768][384]
  ushort* WT5  = (ushort*)(ws + 207486976ull);  // W_proj^T [768][192]
  ushort* WT6  = (ushort*)(ws + 207781888ull);  // Wkv^T    [768][768]
  ushort* WTga = (ushort*)(ws + 208961536ull);  // W_ga^T   [16][1536]
  ushort* cent = (ushort*)(ws + 209010688ull);  // [2048][192] bf16
  ushort* nc   = (ushort*)(ws + 209797120ull);  // [2048][768] bf16
  ushort* k_bf = (ushort*)(ws + 212942848ull);  // [2048][384] bf16
  ushort* vT_bf= (ushort*)(ws + 214515712ull);  // [32][384][64] bf16
  // feaT lives in d_out (exactly 100,663,296 bytes), dead before final GEMM
  ushort* feaT = (ushort*)d_out;

  dim3 blk(256);
  // 1. conversions / weight transposes
  cvt_kernel<<<dim3((Nrows * Dn / 4 + 255) / 256), blk, 0, stream>>>(
      x, xb, Nrows * Dn / 4);
  tconv_kernel<<<dim3(EFn / 32, Dn / 32), blk, 0, stream>>>(W_exp, WT1, Dn, EFn);
  tconv_kernel<<<dim3(512 / 32, EFn / 32), blk, 0, stream>>>(cw, WT2, EFn, 512);
  tconv_kernel<<<dim3(Pn / 32, Dn / 32), blk, 0, stream>>>(Wq, WT3, Dn, Pn);
  tconv_kernel<<<dim3(Dn / 32, Pn / 32), blk, 0, stream>>>(Wp2, WT4, Pn, Dn);
  tconv_kernel<<<dim3(Dn / 32, GFSn / 32), blk, 0, stream>>>(W_proj, WT5, GFSn, Dn);
  tconv_kernel<<<dim3(Dn / 32, Dn / 32), blk, 0, stream>>>(Wkv, WT6, Dn, Dn);
  gawt_kernel<<<dim3(EFn / 256), blk, 0, stream>>>(W_ga, WTga);
  // 2. fea = bf16(x @ W_exp + b_exp); fused feaT write
  gemm_bf16<1, 1><<<dim3(EFn / 128, Nrows / 128), blk, 0, stream>>>(
      xb, WT1, b_exp, fea, feaT, Nrows, EFn, Dn,
      nullptr, nullptr, nullptr, nullptr, nullptr, nullptr);
  // 3. q = bf16(x @ Wq + bq)   (last consumer of xb)
  gemm_bf16<1, 0><<<dim3(Pn / 128, Nrows / 128), blk, 0, stream>>>(
      xb, WT3, bq, q_bf, nullptr, Nrows, Pn, Dn,
      nullptr, nullptr, nullptr, nullptr, nullptr, nullptr);
  // 4. ga = sigmoid(fea @ W_ga + b_ga)  (MFMA)
  gemm_ga<<<dim3(Nrows / 128), blk, 0, stream>>>(fea, WTga, b_ga, ga);
  // 5. actT = softmax-gemm(cw^T @ fea^T)
  gemm_sm<<<dim3(Nrows / 128, 512 / 128), blk, 0, stream>>>(
      WT2, fea, bn1_g, bn1_b, bn1_m, bn1_v, ga, actT);
  // 6. cent = sum_g actT_g @ feaT_g^T  -> bf16
  cent_mfma<<<dim3(Bn * Gn * 2), blk, 0, stream>>>(actT, feaT, part);
  cent_reduce8<<<dim3(393216 / 256), blk, 0, stream>>>(part, cent);
  // 7. nc = bf16(BN2(cent @ W_proj + b_proj))   (MFMA, M=2048,N=768,K=192)
  gemm_bf16<2, 0><<<dim3(Dn / 128, 2048 / 128), blk, 0, stream>>>(
      cent, WT5, b_proj, nc, nullptr, 2048, Dn, GFSn,
      bn2_g, bn2_b, bn2_m, bn2_v, nullptr, nullptr);
  // 8. kv = nc @ Wkv + bkv -> k_bf, vT_bf   (MFMA, M=2048,N=768,K=768)
  gemm_bf16<3, 0><<<dim3(Dn / 128, 2048 / 128), blk, 0, stream>>>(
      nc, WT6, bkv, nullptr, nullptr, 2048, Dn, Dn,
      nullptr, nullptr, nullptr, nullptr, k_bf, vT_bf);
  // 9. attention
  attn_mfma<<<dim3(Nrows / 128), blk, 0, stream>>>(q_bf, k_bf, vT_bf, aout);
  // 10. out = aout @ Wp2 + bp2  (overwrites feaT scratch)
  gemm_bf16<0, 0><<<dim3(Dn / 128, Nrows / 128), blk, 0, stream>>>(
      aout, WT4, bp2, out, nullptr, Nrows, Dn, Pn,
      nullptr, nullptr, nullptr, nullptr, nullptr, nullptr);
}

// Round 8
// 465.408 us; speedup vs baseline: 1.6552x; 1.0373x over previous
//
#include <hip/hip_runtime.h>
#include <hip/hip_bf16.h>

#define EPSV 1e-5f

namespace {
constexpr int Bn = 32, Sn = 1024, Dn = 768, Gn = 8, Cn = 64, Pn = 384;
constexpr int EFn = 1536, GFSn = 192, Nrows = Bn * Sn;  // 32768
}

typedef __attribute__((ext_vector_type(8))) short short8;
typedef __attribute__((ext_vector_type(4))) float f32x4;
typedef __attribute__((ext_vector_type(16))) float f32x16;

__device__ __forceinline__ ushort f2bf(float f) {
  uint u = __builtin_bit_cast(uint, f);
  uint r = (u + 0x7fffu + ((u >> 16) & 1u)) >> 16;
  return (ushort)r;
}
__device__ __forceinline__ uint pack2bf(float lo, float hi) {
  return (uint)f2bf(lo) | ((uint)f2bf(hi) << 16);
}
__device__ __forceinline__ float bf2f(ushort h) {
  return __builtin_bit_cast(float, (uint)h << 16);
}
__device__ __forceinline__ void load16(const ushort* g, ushort* l) {
  __builtin_amdgcn_global_load_lds(
      (const __attribute__((address_space(1))) void*)g,
      (__attribute__((address_space(3))) void*)l, 16, 0, 0);
}
// T1 bijective XCD swizzle (m204)
__device__ __forceinline__ int xcd_lid() {
  const int nbx = gridDim.x;
  const int nwg = nbx * gridDim.y;
  const int orig = blockIdx.y * nbx + blockIdx.x;
  const int xq = nwg >> 3, xr = nwg & 7;
  const int xcd = orig & 7, xi = orig >> 3;
  return (xcd < xr ? xcd * (xq + 1) : xr * (xq + 1) + (xcd - xr) * xq) + xi;
}

// ---------------------------------------------------------------------------
// bf16 MFMA GEMM: 128x128 tile, BK=32, 4 waves (2x2), counted-vmcnt pipeline,
// XCD swizzle, T2 XOR LDS swizzle (seg' = seg ^ ((row>>1)&3), both-sides via
// pre-swizzled global source — rule 21). Breaks the 8-way bank conflict of
// 64B-row tiles (lanes spread 2-per-slot over 8 slots = free).
// Epilogue MODE: 0 f32 out; 1 bf16 out (TRANS=1: +C^T to Ct); 2 bf16+BN2;
// 3 kv split.
// ---------------------------------------------------------------------------
template <int MODE, int TRANS>
__global__ __launch_bounds__(256) void gemm_bf16(
    const ushort* __restrict__ A, const ushort* __restrict__ BT,
    const float* __restrict__ bias, void* __restrict__ Cout,
    ushort* __restrict__ Ct, int M, int N, int K,
    const float* __restrict__ g2, const float* __restrict__ b2,
    const float* __restrict__ m2, const float* __restrict__ v2,
    ushort* __restrict__ kq, ushort* __restrict__ vt) {
  __shared__ ushort sh[16384];  // 2 x (As 4096 | Bs 4096); epilogue staging
  const int tid = threadIdx.x;
  const int wave = tid >> 6, lane = tid & 63;
  const int nbx = gridDim.x;
  const int lid = xcd_lid();
  const int gm = (lid / nbx) * 128, gn = (lid % nbx) * 128;
  const int wr = wave >> 1, wc = wave & 1;

  // staging source: pre-swizzled k-segment (T2, write side)
  const int sws = ((tid & 3) ^ ((tid >> 3) & 3)) * 8;
  const int c0 = tid, c1 = tid + 256;
  const ushort* gA0 = A + (size_t)(gm + (c0 >> 2)) * K + sws;
  const ushort* gA1 = A + (size_t)(gm + (c1 >> 2)) * K + sws;
  const ushort* gB0 = BT + (size_t)(gn + (c0 >> 2)) * K + sws;
  const ushort* gB1 = BT + (size_t)(gn + (c1 >> 2)) * K + sws;

  f32x4 acc[4][4] = {};
  const int l15 = lane & 15;
  const int arow = wr * 64 + l15;
  const int brow = wc * 64 + l15;
  // read side: same XOR (involution)
  const int kswz = (((lane >> 4) ^ ((l15 >> 1) & 3))) * 8;
  const int nk = K >> 5;

#define GB_STAGE(buf, k0)                                    \
  {                                                          \
    load16(gA0 + (k0), &sh[(buf)*8192 + wave * 512]);        \
    load16(gA1 + (k0), &sh[(buf)*8192 + 2048 + wave * 512]); \
    load16(gB0 + (k0), &sh[(buf)*8192 + 4096 + wave * 512]); \
    load16(gB1 + (k0), &sh[(buf)*8192 + 6144 + wave * 512]); \
  }

  GB_STAGE(0, 0);
  for (int t = 0; t < nk; ++t) {
    const int buf = t & 1;
    if (t + 1 < nk) {
      GB_STAGE(buf ^ 1, (t + 1) * 32);
      __builtin_amdgcn_sched_barrier(0);
      asm volatile("s_waitcnt vmcnt(4)" ::: "memory");
    } else {
      asm volatile("s_waitcnt vmcnt(0)" ::: "memory");
    }
    __builtin_amdgcn_s_barrier();       // B1: tile-t LDS valid
    __builtin_amdgcn_sched_barrier(0);  // pin ds_reads below B1
    short8 a[4], b[4];
#pragma unroll
    for (int m = 0; m < 4; ++m)
      a[m] = *reinterpret_cast<const short8*>(
          &sh[buf * 8192 + (arow + m * 16) * 32 + kswz]);
#pragma unroll
    for (int n = 0; n < 4; ++n)
      b[n] = *reinterpret_cast<const short8*>(
          &sh[buf * 8192 + 4096 + (brow + n * 16) * 32 + kswz]);
#pragma unroll
    for (int m = 0; m < 4; ++m)
#pragma unroll
      for (int n = 0; n < 4; ++n)
        acc[m][n] = __builtin_amdgcn_mfma_f32_16x16x32_bf16(
            a[m], b[n], acc[m][n], 0, 0, 0);
    __builtin_amdgcn_s_barrier();       // B2: reads of buf[t&1] done
    __builtin_amdgcn_sched_barrier(0);
  }
#undef GB_STAGE

  // epilogue: C/D layout col=lane&15, row=(lane>>4)*4+j
  const int crow0 = gm + wr * 64 + (lane >> 4) * 4;
  const int ccol0 = gn + wc * 64 + l15;
  float sc_[4][4], sf_[4][4];
  if (MODE == 2) {
#pragma unroll
    for (int m = 0; m < 4; ++m)
#pragma unroll
      for (int j = 0; j < 4; ++j) {
        const int c = (crow0 + m * 16 + j) & 63;
        const float s = g2[c] * rsqrtf(v2[c] + EPSV);
        sc_[m][j] = s;
        sf_[m][j] = b2[c] - m2[c] * s;
      }
  }
  alignas(8) ushort cb[4][4][4];
#pragma unroll
  for (int m = 0; m < 4; ++m)
#pragma unroll
    for (int n = 0; n < 4; ++n) {
      const int col = ccol0 + n * 16;
      const float bv = bias ? bias[col] : 0.f;
#pragma unroll
      for (int j = 0; j < 4; ++j) {
        const int row = crow0 + m * 16 + j;
        float v = acc[m][n][j] + bv;
        if (MODE == 0) {
          ((float*)Cout)[(size_t)row * N + col] = v;
        } else if (MODE == 1) {
          const ushort h = f2bf(v);
          ((ushort*)Cout)[(size_t)row * N + col] = h;
          if (TRANS) cb[m][n][j] = h;
        } else if (MODE == 2) {
          v = v * sc_[m][j] + sf_[m][j];
          ((ushort*)Cout)[(size_t)row * N + col] = f2bf(v);
        } else {  // MODE 3: kv split
          const ushort h = f2bf(v);
          if (col < 384) {
            kq[(size_t)row * 384 + col] = h;
          } else {
            vt[(size_t)(row >> 6) * 24576 + (size_t)(col - 384) * 64 +
               (row & 63)] = h;
          }
        }
      }
    }

  if (TRANS) {
    // restage transposed tile through LDS (stride 136), coalesced 16B stores
    const int l4 = lane >> 4;
#pragma unroll
    for (int p = 0; p < 2; ++p) {
      __syncthreads();
      if (wc == p) {
#pragma unroll
        for (int n = 0; n < 4; ++n) {
          const int cl = n * 16 + l15;
#pragma unroll
          for (int m = 0; m < 4; ++m) {
            const int r = wr * 64 + m * 16 + l4 * 4;
            *reinterpret_cast<ushort4*>(&sh[cl * 136 + r]) =
                *reinterpret_cast<const ushort4*>(&cb[m][n][0]);
          }
        }
      }
      __syncthreads();
      const int cl = tid >> 2, seg = tid & 3;
      const ushort* src = &sh[cl * 136 + seg * 32];
      ushort* dst = Ct + (size_t)(gn + p * 64 + cl) * M + gm + seg * 32;
      *reinterpret_cast<uint4*>(dst) = *reinterpret_cast<const uint4*>(src);
      *reinterpret_cast<uint4*>(dst + 8) =
          *reinterpret_cast<const uint4*>(src + 8);
      *reinterpret_cast<uint4*>(dst + 16) =
          *reinterpret_cast<const uint4*>(src + 16);
      *reinterpret_cast<uint4*>(dst + 24) =
          *reinterpret_cast<const uint4*>(src + 24);
    }
  }
}

// ---------------------------------------------------------------------------
// gemm_ga: ga[32768][8] = sigmoid(fea @ W_ga + b_ga) via MFMA, counted vmcnt,
// T2 swizzle both-sides.
// ---------------------------------------------------------------------------
__global__ __launch_bounds__(256) void gemm_ga(
    const ushort* __restrict__ fea, const ushort* __restrict__ WTga,
    const float* __restrict__ b_ga, float* __restrict__ ga) {
  constexpr int K = EFn;
  __shared__ ushort sh[9216];  // 2 x (As 4096 | Bs 512)
  const int tid = threadIdx.x;
  const int wave = tid >> 6, lane = tid & 63;
  const int gm = blockIdx.x * 128;

  const int sws = ((tid & 3) ^ ((tid >> 3) & 3)) * 8;
  const int swsB = ((lane & 3) ^ ((lane >> 3) & 3)) * 8;
  const int c0 = tid, c1 = tid + 256;
  const ushort* gA0 = fea + (size_t)(gm + (c0 >> 2)) * K + sws;
  const ushort* gA1 = fea + (size_t)(gm + (c1 >> 2)) * K + sws;
  const ushort* gB = WTga + (size_t)(lane >> 2) * K + swsB;

  f32x4 acc[2] = {};
  const int l15 = lane & 15, l4 = lane >> 4;
  const int kswz = ((l4 ^ ((l15 >> 1) & 3))) * 8;

#define GA_STAGE(buf, k0)                                     \
  {                                                           \
    load16(gA0 + (k0), &sh[(buf)*4608 + wave * 512]);         \
    load16(gA1 + (k0), &sh[(buf)*4608 + 2048 + wave * 512]);  \
    if (wave == 0) load16(gB + (k0), &sh[(buf)*4608 + 4096]); \
  }

  GA_STAGE(0, 0);
  for (int t = 0; t < K / 32; ++t) {
    const int buf = t & 1;
    if (t + 1 < K / 32) {
      GA_STAGE(buf ^ 1, (t + 1) * 32);
      __builtin_amdgcn_sched_barrier(0);
      asm volatile("s_waitcnt vmcnt(2)" ::: "memory");
    } else {
      asm volatile("s_waitcnt vmcnt(0)" ::: "memory");
    }
    __builtin_amdgcn_s_barrier();
    __builtin_amdgcn_sched_barrier(0);
    const short8 b = *reinterpret_cast<const short8*>(
        &sh[buf * 4608 + 4096 + l15 * 32 + kswz]);
    short8 a[2];
#pragma unroll
    for (int mi = 0; mi < 2; ++mi)
      a[mi] = *reinterpret_cast<const short8*>(
          &sh[buf * 4608 + (wave * 32 + mi * 16 + l15) * 32 + kswz]);
#pragma unroll
    for (int mi = 0; mi < 2; ++mi)
      acc[mi] =
          __builtin_amdgcn_mfma_f32_16x16x32_bf16(a[mi], b, acc[mi], 0, 0, 0);
    __builtin_amdgcn_s_barrier();
    __builtin_amdgcn_sched_barrier(0);
  }
#undef GA_STAGE

  if (l15 < 8) {
    const float bv = b_ga[l15];
#pragma unroll
    for (int mi = 0; mi < 2; ++mi)
#pragma unroll
      for (int j = 0; j < 4; ++j) {
        const int row = gm + wave * 32 + mi * 16 + l4 * 4 + j;
        const float v = acc[mi][j] + bv;
        ga[(size_t)row * 8 + l15] = 1.0f / (1.0f + expf(-v));
      }
  }
}

// ---------------------------------------------------------------------------
// gemm_sm: actT[512][32768] = softmax-epilogue( WT2 @ fea^T ).
// Counted-vmcnt, gm-fastest XCD mapping, T2 swizzle both-sides.
// ---------------------------------------------------------------------------
__global__ __launch_bounds__(256) void gemm_sm(
    const ushort* __restrict__ A, const ushort* __restrict__ BT,
    const float* __restrict__ g1, const float* __restrict__ b1,
    const float* __restrict__ m1, const float* __restrict__ v1,
    const float* __restrict__ ga, ushort* __restrict__ actT) {
  constexpr int K = EFn, N = Nrows;
  __shared__ ushort sh[16384];
  __shared__ float sScale[128], sShift[128];
  const int tid = threadIdx.x;
  const int wave = tid >> 6, lane = tid & 63;
  const int lid = xcd_lid();           // 0..1023
  const int gm = (lid & 3) * 128;      // gm fastest within XCD chunk
  const int gn = (lid >> 2) * 128;
  const int wr = wave >> 1, wc = wave & 1;

  if (tid < 128) {
    const int row = gm + tid;
    const float sc = g1[row] * rsqrtf(v1[row] + EPSV);
    sScale[tid] = sc;
    sShift[tid] = b1[row] - m1[row] * sc;
  }

  const int sws = ((tid & 3) ^ ((tid >> 3) & 3)) * 8;
  const int c0 = tid, c1 = tid + 256;
  const ushort* gA0 = A + (size_t)(gm + (c0 >> 2)) * K + sws;
  const ushort* gA1 = A + (size_t)(gm + (c1 >> 2)) * K + sws;
  const ushort* gB0 = BT + (size_t)(gn + (c0 >> 2)) * K + sws;
  const ushort* gB1 = BT + (size_t)(gn + (c1 >> 2)) * K + sws;

  f32x4 acc[4][4] = {};
  const int l15 = lane & 15;
  const int arow = wr * 64 + l15;
  const int brow = wc * 64 + l15;
  const int kswz = (((lane >> 4) ^ ((l15 >> 1) & 3))) * 8;
  const int nk = K >> 5;

#define SM_STAGE(buf, k0)                                    \
  {                                                          \
    load16(gA0 + (k0), &sh[(buf)*8192 + wave * 512]);        \
    load16(gA1 + (k0), &sh[(buf)*8192 + 2048 + wave * 512]); \
    load16(gB0 + (k0), &sh[(buf)*8192 + 4096 + wave * 512]); \
    load16(gB1 + (k0), &sh[(buf)*8192 + 6144 + wave * 512]); \
  }

  SM_STAGE(0, 0);
  for (int t = 0; t < nk; ++t) {
    const int buf = t & 1;
    if (t + 1 < nk) {
      SM_STAGE(buf ^ 1, (t + 1) * 32);
      __builtin_amdgcn_sched_barrier(0);
      asm volatile("s_waitcnt vmcnt(4)" ::: "memory");
    } else {
      asm volatile("s_waitcnt vmcnt(0)" ::: "memory");
    }
    __builtin_amdgcn_s_barrier();
    __builtin_amdgcn_sched_barrier(0);
    short8 a[4], b[4];
#pragma unroll
    for (int m = 0; m < 4; ++m)
      a[m] = *reinterpret_cast<const short8*>(
          &sh[buf * 8192 + (arow + m * 16) * 32 + kswz]);
#pragma unroll
    for (int n = 0; n < 4; ++n)
      b[n] = *reinterpret_cast<const short8*>(
          &sh[buf * 8192 + 4096 + (brow + n * 16) * 32 + kswz]);
#pragma unroll
    for (int m = 0; m < 4; ++m)
#pragma unroll
      for (int n = 0; n < 4; ++n)
        acc[m][n] = __builtin_amdgcn_mfma_f32_16x16x32_bf16(
            a[m], b[n], acc[m][n], 0, 0, 0);
    __builtin_amdgcn_s_barrier();
    __builtin_amdgcn_sched_barrier(0);
  }
#undef SM_STAGE

  const int l4 = lane >> 4;
  const int g = (gm >> 6) + wr;
#pragma unroll
  for (int n = 0; n < 4; ++n) {
    const int col = gn + wc * 64 + n * 16 + l15;
    float mx = -1e30f;
#pragma unroll
    for (int m = 0; m < 4; ++m)
#pragma unroll
      for (int j = 0; j < 4; ++j) {
        const int rl = wr * 64 + m * 16 + l4 * 4 + j;
        acc[m][n][j] = acc[m][n][j] * sScale[rl] + sShift[rl];
        mx = fmaxf(mx, acc[m][n][j]);
      }
    mx = fmaxf(mx, __shfl_xor(mx, 16));
    mx = fmaxf(mx, __shfl_xor(mx, 32));
    float sum = 0.f;
#pragma unroll
    for (int m = 0; m < 4; ++m)
#pragma unroll
      for (int j = 0; j < 4; ++j) {
        acc[m][n][j] = expf(acc[m][n][j] - mx);
        sum += acc[m][n][j];
      }
    sum += __shfl_xor(sum, 16);
    sum += __shfl_xor(sum, 32);
    const float sc = ga[(size_t)col * 8 + g] / sum;
#pragma unroll
    for (int m = 0; m < 4; ++m)
#pragma unroll
      for (int j = 0; j < 4; ++j) {
        const int rowg = gm + wr * 64 + m * 16 + l4 * 4 + j;
        actT[(size_t)rowg * N + col] = f2bf(acc[m][n][j] * sc);
      }
  }
}

// ---------------------------------------------------------------------------
__global__ __launch_bounds__(256) void cvt_kernel(const float* __restrict__ in,
                                                  ushort* __restrict__ out,
                                                  int n4) {
  const int i = blockIdx.x * 256 + threadIdx.x;
  if (i >= n4) return;
  const float4 v = reinterpret_cast<const float4*>(in)[i];
  ushort4 o;
  o.x = f2bf(v.x); o.y = f2bf(v.y); o.z = f2bf(v.z); o.w = f2bf(v.w);
  reinterpret_cast<ushort4*>(out)[i] = o;
}

// ---------------------------------------------------------------------------
// transpose + convert: in f32 [R][C] -> out bf16 [C][R]
// ---------------------------------------------------------------------------
__global__ __launch_bounds__(256) void tconv_kernel(const float* __restrict__ in,
                                                    ushort* __restrict__ out,
                                                    int R, int C) {
  __shared__ float t[32][33];
  const int tx = threadIdx.x & 31, ty = threadIdx.x >> 5;
  const int bc = blockIdx.x * 32, br = blockIdx.y * 32;
#pragma unroll
  for (int i = 0; i < 32; i += 8)
    t[ty + i][tx] = in[(size_t)(br + ty + i) * C + bc + tx];
  __syncthreads();
#pragma unroll
  for (int i = 0; i < 32; i += 8)
    out[(size_t)(bc + ty + i) * R + br + tx] = f2bf(t[tx][ty + i]);
}

// ---------------------------------------------------------------------------
// W_ga [1536][8] f32 -> WTga [16][1536] bf16 (rows 8..15 zero)
// ---------------------------------------------------------------------------
__global__ __launch_bounds__(256) void gawt_kernel(const float* __restrict__ in,
                                                   ushort* __restrict__ out) {
  const int k = blockIdx.x * 256 + threadIdx.x;  // 0..1535
#pragma unroll
  for (int g = 0; g < 8; ++g) {
    out[(size_t)g * EFn + k] = f2bf(in[(size_t)k * 8 + g]);
    out[(size_t)(g + 8) * EFn + k] = 0;
  }
}

// ---------------------------------------------------------------------------
// cent_mfma: block per (b,g,ch) — s split in 2 chunks of 512 for occupancy.
// part[bid][c=64][f=192]. Already fully bank-swizzled (128B rows, 3-bit XOR).
// ---------------------------------------------------------------------------
__global__ __launch_bounds__(256) void cent_mfma(
    const ushort* __restrict__ actT, const ushort* __restrict__ feaT,
    float* __restrict__ part) {
  __shared__ ushort As[2][64 * 64];
  __shared__ ushort Bs[2][192 * 64];
  const int tid = threadIdx.x;
  const int wave = tid >> 6, lane = tid & 63;
  const int b = blockIdx.x >> 4;
  const int g = (blockIdx.x >> 1) & 7;
  const int ch = blockIdx.x & 1;
  const size_t colbase = (size_t)b * 1024 + ch * 512;
  const int srow = tid >> 2, scp = (tid & 3) * 2;
  const ushort* gA = actT + (size_t)(g * 64 + srow) * Nrows + colbase;
  const ushort* gB0 = feaT + (size_t)(g * 192 + srow) * Nrows + colbase;
  const ushort* gB1 = gB0 + (size_t)64 * Nrows;
  const ushort* gB2 = gB0 + (size_t)128 * Nrows;

  uint4 ra[2], rb0[2], rb1[2], rb2[2];
  f32x4 acc[4][3] = {};
  const int l15 = lane & 15, hi = lane >> 4;
  const int sw = srow & 7;

#define CM_ISSUE(k0)                                                    \
  {                                                                     \
    _Pragma("unroll") for (int i = 0; i < 2; ++i) {                     \
      const int off = (k0) + (scp + i) * 8;                             \
      ra[i] = *reinterpret_cast<const uint4*>(gA + off);                \
      rb0[i] = *reinterpret_cast<const uint4*>(gB0 + off);              \
      rb1[i] = *reinterpret_cast<const uint4*>(gB1 + off);              \
      rb2[i] = *reinterpret_cast<const uint4*>(gB2 + off);              \
    }                                                                   \
  }
#define CM_STASH(buf)                                                   \
  {                                                                     \
    _Pragma("unroll") for (int i = 0; i < 2; ++i) {                     \
      const int c = scp + i;                                            \
      *reinterpret_cast<uint4*>(&As[buf][srow * 64 + ((c ^ sw) * 8)]) = \
          ra[i];                                                        \
      *reinterpret_cast<uint4*>(&Bs[buf][srow * 64 + ((c ^ sw) * 8)]) = \
          rb0[i];                                                       \
      *reinterpret_cast<uint4*>(                                        \
          &Bs[buf][(64 + srow) * 64 + ((c ^ sw) * 8)]) = rb1[i];        \
      *reinterpret_cast<uint4*>(                                        \
          &Bs[buf][(128 + srow) * 64 + ((c ^ sw) * 8)]) = rb2[i];       \
    }                                                                   \
  }

  CM_ISSUE(0);
  CM_STASH(0);
  for (int kk = 0; kk < 8; ++kk) {
    const int buf = kk & 1;
    __syncthreads();
    if (kk < 7) CM_ISSUE((kk + 1) * 64);
#pragma unroll
    for (int ks = 0; ks < 2; ++ks) {
      const int chh = ks * 4 + hi;
      short8 a[4], bb[3];
#pragma unroll
      for (int m = 0; m < 4; ++m) {
        const int r = m * 16 + l15;
        a[m] = *reinterpret_cast<const short8*>(
            &As[buf][r * 64 + ((chh ^ (r & 7)) * 8)]);
      }
#pragma unroll
      for (int nn = 0; nn < 3; ++nn) {
        const int r = wave * 48 + nn * 16 + l15;
        bb[nn] = *reinterpret_cast<const short8*>(
            &Bs[buf][r * 64 + ((chh ^ (r & 7)) * 8)]);
      }
#pragma unroll
      for (int m = 0; m < 4; ++m)
#pragma unroll
        for (int nn = 0; nn < 3; ++nn)
          acc[m][nn] = __builtin_amdgcn_mfma_f32_16x16x32_bf16(
              a[m], bb[nn], acc[m][nn], 0, 0, 0);
    }
    if (kk < 7) CM_STASH(buf ^ 1);
  }
#undef CM_ISSUE
#undef CM_STASH

  float* pb = part + (size_t)blockIdx.x * 12288;
#pragma unroll
  for (int m = 0; m < 4; ++m)
#pragma unroll
    for (int nn = 0; nn < 3; ++nn) {
      const int col = wave * 48 + nn * 16 + l15;
#pragma unroll
      for (int j = 0; j < 4; ++j) {
        const int row = m * 16 + hi * 4 + j;
        pb[row * 192 + col] = acc[m][nn][j];
      }
    }
}

// reduce over (g,ch) -> cent bf16 [2048][192]
__global__ __launch_bounds__(256) void cent_reduce8(
    const float* __restrict__ part, ushort* __restrict__ cent) {
  const int idx = blockIdx.x * 256 + threadIdx.x;  // < 393216
  const int b = idx / 12288, r = idx % 12288;
  float s = 0.f;
#pragma unroll
  for (int j = 0; j < 16; ++j) s += part[(size_t)(b * 16 + j) * 12288 + r];
  cent[idx] = f2bf(s);
}

// ---------------------------------------------------------------------------
// MFMA attention (verified R3): one wave per 32 q-rows, all-register.
// ---------------------------------------------------------------------------
__global__ __launch_bounds__(256) void attn_mfma(
    const ushort* __restrict__ qb, const ushort* __restrict__ kb,
    const ushort* __restrict__ vtb, ushort* __restrict__ aout) {
  const int wave = threadIdx.x >> 6, lane = threadIdx.x & 63;
  const int wrow = blockIdx.x * 4 + wave;
  const int row0 = wrow * 32;
  const int b = row0 >> 10;
  const int l31 = lane & 31, hi = lane >> 5;

  f32x16 accs0 = 0.f, accs1 = 0.f;
  const ushort* qp = qb + (size_t)(row0 + l31) * 384 + hi * 8;
  const ushort* kp = kb + (size_t)(b * 64 + l31) * 384 + hi * 8;
#pragma unroll 4
  for (int ks = 0; ks < 24; ++ks) {
    const short8 bq = *reinterpret_cast<const short8*>(qp + ks * 16);
    const short8 a0 = *reinterpret_cast<const short8*>(kp + ks * 16);
    const short8 a1 = *reinterpret_cast<const short8*>(kp + 32 * 384 + ks * 16);
    accs0 = __builtin_amdgcn_mfma_f32_32x32x16_bf16(a0, bq, accs0, 0, 0, 0);
    accs1 = __builtin_amdgcn_mfma_f32_32x32x16_bf16(a1, bq, accs1, 0, 0, 0);
  }

  const float alpha = 0.05103103630798287f;
  float p[32];
#pragma unroll
  for (int i = 0; i < 16; ++i) { p[i] = accs0[i]; p[16 + i] = accs1[i]; }
  float mx = p[0];
#pragma unroll
  for (int i = 1; i < 32; ++i) mx = fmaxf(mx, p[i]);
  mx = fmaxf(mx, __shfl_xor(mx, 32));
  float sum = 0.f;
#pragma unroll
  for (int i = 0; i < 32; ++i) {
    p[i] = expf((p[i] - mx) * alpha);
    sum += p[i];
  }
  sum += __shfl_xor(sum, 32);
  const float inv = 1.0f / sum;

  uint pk0[8], pk1[8];
#pragma unroll
  for (int ct = 0; ct < 2; ++ct)
#pragma unroll
    for (int rg = 0; rg < 4; ++rg) {
      pk0[ct * 4 + rg] =
          pack2bf(p[ct * 16 + rg * 4 + 0] * inv, p[ct * 16 + rg * 4 + 1] * inv);
      pk1[ct * 4 + rg] =
          pack2bf(p[ct * 16 + rg * 4 + 2] * inv, p[ct * 16 + rg * 4 + 3] * inv);
    }
  uint ex0[8], ex1[8];
#pragma unroll
  for (int i = 0; i < 8; ++i) {
    ex0[i] = __shfl_xor(pk0[i], 32);
    ex1[i] = __shfl_xor(pk1[i], 32);
  }

  const ushort* vp = vtb + ((size_t)b * 384 + l31) * 64 + hi * 8;
  ushort* orow = aout + (size_t)(row0 + l31) * 384;
  for (int mt = 0; mt < 12; ++mt) {
    f32x16 acco = 0.f;
#pragma unroll
    for (int kc = 0; kc < 4; ++kc) {
      const short8 av = *reinterpret_cast<const short8*>(
          vp + (size_t)mt * 32 * 64 + kc * 16);
      const int base = (kc >> 1) * 4 + (kc & 1) * 2;
      const uint o0 = hi ? pk0[base + 1] : pk0[base];
      const uint o1 = hi ? pk1[base + 1] : pk1[base];
      const uint e0 = hi ? ex0[base + 1] : ex0[base];
      const uint e1 = hi ? ex1[base + 1] : ex1[base];
      uint4 uu;
      uu.x = hi ? e0 : o0;
      uu.y = hi ? e1 : o1;
      uu.z = hi ? o0 : e0;
      uu.w = hi ? o1 : e1;
      const short8 bp = __builtin_bit_cast(short8, uu);
      acco = __builtin_amdgcn_mfma_f32_32x32x16_bf16(av, bp, acco, 0, 0, 0);
    }
#pragma unroll
    for (int rg = 0; rg < 4; ++rg) {
      ushort4 ov;
      ov.x = f2bf(acco[rg * 4 + 0]);
      ov.y = f2bf(acco[rg * 4 + 1]);
      ov.z = f2bf(acco[rg * 4 + 2]);
      ov.w = f2bf(acco[rg * 4 + 3]);
      *reinterpret_cast<ushort4*>(&orow[mt * 32 + rg * 8 + hi * 4]) = ov;
    }
  }
}

// ---------------------------------------------------------------------------
extern "C" void kernel_launch(void* const* d_in, const int* in_sizes, int n_in,
                              void* d_out, int out_size, void* d_ws,
                              size_t ws_size, hipStream_t stream) {
  (void)in_sizes; (void)n_in; (void)out_size; (void)ws_size;
  const float* x      = (const float*)d_in[0];
  const float* W_exp  = (const float*)d_in[1];
  const float* b_exp  = (const float*)d_in[2];
  const float* W_ga   = (const float*)d_in[3];
  const float* b_ga   = (const float*)d_in[4];
  const float* bn1_g  = (const float*)d_in[5];
  const float* bn1_b  = (const float*)d_in[6];
  const float* bn1_m  = (const float*)d_in[7];
  const float* bn1_v  = (const float*)d_in[8];
  const float* cw     = (const float*)d_in[9];
  const float* W_proj = (const float*)d_in[10];
  const float* b_proj = (const float*)d_in[11];
  const float* bn2_g  = (const float*)d_in[12];
  const float* bn2_b  = (const float*)d_in[13];
  const float* bn2_m  = (const float*)d_in[14];
  const float* bn2_v  = (const float*)d_in[15];
  const float* Wq     = (const float*)d_in[16];
  const float* bq     = (const float*)d_in[17];
  const float* Wkv    = (const float*)d_in[18];
  const float* bkv    = (const float*)d_in[19];
  const float* Wp2    = (const float*)d_in[20];
  const float* bp2    = (const float*)d_in[21];
  float* out = (float*)d_out;

  char* ws = (char*)d_ws;
  // region A @0: fea bf16 100.66MB; aout bf16 25.2MB reuse after cent
  ushort* fea  = (ushort*)(ws + 0);
  ushort* aout = (ushort*)(ws + 0);
  // region B: xb 50.3MB; actT bf16 33.6MB reuse after q GEMM
  ushort* xb   = (ushort*)(ws + 100663296ull);
  ushort* actT = (ushort*)(ws + 100663296ull);
  ushort* q_bf = (ushort*)(ws + 150994944ull);  // 25.2MB
  float*  ga   = (float*)(ws + 176160768ull);   // 1MB
  float*  part = (float*)(ws + 177209344ull);   // 25.2MB (512 x 12288 f32)
  ushort* WT1  = (ushort*)(ws + 202375168ull);  // W_exp^T  [1536][768]
  ushort* WT2  = (ushort*)(ws + 204734464ull);  // cw^T     [512][1536]
  ushort* WT3  = (ushort*)(ws + 206307328ull);  // Wq^T     [384][768]
  ushort* WT4  = (ushort*)(ws + 206897152ull);  // Wp2^T    [768][384]
  ushort* WT5  = (ushort*)(ws + 207486976ull);  // W_proj^T [768][192]
  ushort* WT6  = (ushort*)(ws + 207781888ull);  // Wkv^T    [768][768]
  ushort* WTga = (ushort*)(ws + 208961536ull);  // W_ga^T   [16][1536]
  ushort* cent = (ushort*)(ws + 209010688ull);  // [2048][192] bf16
  ushort* nc   = (ushort*)(ws + 209797120ull);  // [2048][768] bf16
  ushort* k_bf = (ushort*)(ws + 212942848ull);  // [2048][384] bf16
  ushort* vT_bf= (ushort*)(ws + 214515712ull);  // [32][384][64] bf16
  // feaT lives in d_out (exactly 100,663,296 bytes), dead before final GEMM
  ushort* feaT = (ushort*)d_out;

  dim3 blk(256);
  // 1. conversions / weight transposes
  cvt_kernel<<<dim3((Nrows * Dn / 4 + 255) / 256), blk, 0, stream>>>(
      x, xb, Nrows * Dn / 4);
  tconv_kernel<<<dim3(EFn / 32, Dn / 32), blk, 0, stream>>>(W_exp, WT1, Dn, EFn);
  tconv_kernel<<<dim3(512 / 32, EFn / 32), blk, 0, stream>>>(cw, WT2, EFn, 512);
  tconv_kernel<<<dim3(Pn / 32, Dn / 32), blk, 0, stream>>>(Wq, WT3, Dn, Pn);
  tconv_kernel<<<dim3(Dn / 32, Pn / 32), blk, 0, stream>>>(Wp2, WT4, Pn, Dn);
  tconv_kernel<<<dim3(Dn / 32, GFSn / 32), blk, 0, stream>>>(W_proj, WT5, GFSn, Dn);
  tconv_kernel<<<dim3(Dn / 32, Dn / 32), blk, 0, stream>>>(Wkv, WT6, Dn, Dn);
  gawt_kernel<<<dim3(EFn / 256), blk, 0, stream>>>(W_ga, WTga);
  // 2. fea = bf16(x @ W_exp + b_exp); fused feaT write
  gemm_bf16<1, 1><<<dim3(EFn / 128, Nrows / 128), blk, 0, stream>>>(
      xb, WT1, b_exp, fea, feaT, Nrows, EFn, Dn,
      nullptr, nullptr, nullptr, nullptr, nullptr, nullptr);
  // 3. q = bf16(x @ Wq + bq)   (last consumer of xb)
  gemm_bf16<1, 0><<<dim3(Pn / 128, Nrows / 128), blk, 0, stream>>>(
      xb, WT3, bq, q_bf, nullptr, Nrows, Pn, Dn,
      nullptr, nullptr, nullptr, nullptr, nullptr, nullptr);
  // 4. ga = sigmoid(fea @ W_ga + b_ga)  (MFMA)
  gemm_ga<<<dim3(Nrows / 128), blk, 0, stream>>>(fea, WTga, b_ga, ga);
  // 5. actT = softmax-gemm(cw^T @ fea^T)
  gemm_sm<<<dim3(Nrows / 128, 512 / 128), blk, 0, stream>>>(
      WT2, fea, bn1_g, bn1_b, bn1_m, bn1_v, ga, actT);
  // 6. cent = sum_g actT_g @ feaT_g^T  -> bf16
  cent_mfma<<<dim3(Bn * Gn * 2), blk, 0, stream>>>(actT, feaT, part);
  cent_reduce8<<<dim3(393216 / 256), blk, 0, stream>>>(part, cent);
  // 7. nc = bf16(BN2(cent @ W_proj + b_proj))   (MFMA, M=2048,N=768,K=192)
  gemm_bf16<2, 0><<<dim3(Dn / 128, 2048 / 128), blk, 0, stream>>>(
      cent, WT5, b_proj, nc, nullptr, 2048, Dn, GFSn,
      bn2_g, bn2_b, bn2_m, bn2_v, nullptr, nullptr);
  // 8. kv = nc @ Wkv + bkv -> k_bf, vT_bf   (MFMA, M=2048,N=768,K=768)
  gemm_bf16<3, 0><<<dim3(Dn / 128, 2048 / 128), blk, 0, stream>>>(
      nc, WT6, bkv, nullptr, nullptr, 2048, Dn, Dn,
      nullptr, nullptr, nullptr, nullptr, k_bf, vT_bf);
  // 9. attention
  attn_mfma<<<dim3(Nrows / 128), blk, 0, stream>>>(q_bf, k_bf, vT_bf, aout);
  // 10. out = aout @ Wp2 + bp2  (overwrites feaT scratch)
  gemm_bf16<0, 0><<<dim3(Dn / 128, Nrows / 128), blk, 0, stream>>>(
      aout, WT4, bp2, out, nullptr, Nrows, Dn, Pn,
      nullptr, nullptr, nullptr, nullptr, nullptr, nullptr);
}

// Round 9
// 404.825 us; speedup vs baseline: 1.9029x; 1.1497x over previous
//
#include <hip/hip_runtime.h>
#include <hip/hip_bf16.h>

#define EPSV 1e-5f

namespace {
constexpr int Bn = 32, Sn = 1024, Dn = 768, Gn = 8, Cn = 64, Pn = 384;
constexpr int EFn = 1536, GFSn = 192, Nrows = Bn * Sn;  // 32768
}

typedef __attribute__((ext_vector_type(8))) short short8;
typedef __attribute__((ext_vector_type(4))) float f32x4;
typedef __attribute__((ext_vector_type(16))) float f32x16;

__device__ __forceinline__ ushort f2bf(float f) {
  uint u = __builtin_bit_cast(uint, f);
  uint r = (u + 0x7fffu + ((u >> 16) & 1u)) >> 16;
  return (ushort)r;
}
__device__ __forceinline__ uint pack2bf(float lo, float hi) {
  return (uint)f2bf(lo) | ((uint)f2bf(hi) << 16);
}
__device__ __forceinline__ float bf2f(ushort h) {
  return __builtin_bit_cast(float, (uint)h << 16);
}
__device__ __forceinline__ void load16(const ushort* g, ushort* l) {
  __builtin_amdgcn_global_load_lds(
      (const __attribute__((address_space(1))) void*)g,
      (__attribute__((address_space(3))) void*)l, 16, 0, 0);
}
// T1 bijective XCD swizzle (m204)
__device__ __forceinline__ int xcd_lid() {
  const int nbx = gridDim.x;
  const int nwg = nbx * gridDim.y;
  const int orig = blockIdx.y * nbx + blockIdx.x;
  const int xq = nwg >> 3, xr = nwg & 7;
  const int xcd = orig & 7, xi = orig >> 3;
  return (xcd < xr ? xcd * (xq + 1) : xr * (xq + 1) + (xcd - xr) * xq) + xi;
}

// ---------------------------------------------------------------------------
// bf16 MFMA GEMM: 128x128 tile, BK=32, 4 waves (2x2), DEPTH-3 counted-vmcnt
// pipeline (tiles t+1,t+2 = 8 loads stay in flight across barriers; vmcnt(8)
// waits only tile t), XCD swizzle, T2 XOR LDS swizzle both-sides.
// Epilogue MODE: 0 f32 out; 1 bf16 out; 2 bf16+BN2 (row%64); 3 kv split.
// ---------------------------------------------------------------------------
template <int MODE>
__global__ __launch_bounds__(256) void gemm_bf16(
    const ushort* __restrict__ A, const ushort* __restrict__ BT,
    const float* __restrict__ bias, void* __restrict__ Cout,
    int M, int N, int K,
    const float* __restrict__ g2, const float* __restrict__ b2,
    const float* __restrict__ m2, const float* __restrict__ v2,
    ushort* __restrict__ kq, ushort* __restrict__ vt) {
  __shared__ ushort sh[24576];  // 3 x (As 4096 | Bs 4096) ushorts = 48 KB
  const int tid = threadIdx.x;
  const int wave = tid >> 6, lane = tid & 63;
  const int nbx = gridDim.x;
  const int lid = xcd_lid();
  const int gm = (lid / nbx) * 128, gn = (lid % nbx) * 128;
  const int wr = wave >> 1, wc = wave & 1;

  // staging source: pre-swizzled k-segment (T2, write side)
  const int sws = ((tid & 3) ^ ((tid >> 3) & 3)) * 8;
  const int c0 = tid, c1 = tid + 256;
  const ushort* gA0 = A + (size_t)(gm + (c0 >> 2)) * K + sws;
  const ushort* gA1 = A + (size_t)(gm + (c1 >> 2)) * K + sws;
  const ushort* gB0 = BT + (size_t)(gn + (c0 >> 2)) * K + sws;
  const ushort* gB1 = BT + (size_t)(gn + (c1 >> 2)) * K + sws;

  f32x4 acc[4][4] = {};
  const int l15 = lane & 15;
  const int arow = wr * 64 + l15;
  const int brow = wc * 64 + l15;
  const int kswz = (((lane >> 4) ^ ((l15 >> 1) & 3))) * 8;
  const int nk = K >> 5;

#define GB_STAGE(buf, k0)                                    \
  {                                                          \
    load16(gA0 + (k0), &sh[(buf)*8192 + wave * 512]);        \
    load16(gA1 + (k0), &sh[(buf)*8192 + 2048 + wave * 512]); \
    load16(gB0 + (k0), &sh[(buf)*8192 + 4096 + wave * 512]); \
    load16(gB1 + (k0), &sh[(buf)*8192 + 6144 + wave * 512]); \
  }

  GB_STAGE(0, 0);
  GB_STAGE(1, 32);
  int bc = 0;  // current buffer
  for (int t = 0; t < nk; ++t) {
    if (t + 2 < nk) {
      const int bp = (bc == 0) ? 2 : bc - 1;  // (bc+2)%3
      GB_STAGE(bp, (t + 2) * 32);
      __builtin_amdgcn_sched_barrier(0);
      asm volatile("s_waitcnt vmcnt(8)" ::: "memory");
    } else if (t + 1 < nk) {
      asm volatile("s_waitcnt vmcnt(4)" ::: "memory");
    } else {
      asm volatile("s_waitcnt vmcnt(0)" ::: "memory");
    }
    __builtin_amdgcn_s_barrier();       // B1: tile-t LDS valid
    __builtin_amdgcn_sched_barrier(0);  // pin ds_reads below B1
    short8 a[4], b[4];
#pragma unroll
    for (int m = 0; m < 4; ++m)
      a[m] = *reinterpret_cast<const short8*>(
          &sh[bc * 8192 + (arow + m * 16) * 32 + kswz]);
#pragma unroll
    for (int n = 0; n < 4; ++n)
      b[n] = *reinterpret_cast<const short8*>(
          &sh[bc * 8192 + 4096 + (brow + n * 16) * 32 + kswz]);
#pragma unroll
    for (int m = 0; m < 4; ++m)
#pragma unroll
      for (int n = 0; n < 4; ++n)
        acc[m][n] = __builtin_amdgcn_mfma_f32_16x16x32_bf16(
            a[m], b[n], acc[m][n], 0, 0, 0);
    __builtin_amdgcn_s_barrier();       // B2: reads of buf bc done
    __builtin_amdgcn_sched_barrier(0);
    bc = (bc == 2) ? 0 : bc + 1;
  }
#undef GB_STAGE

  // epilogue: C/D layout col=lane&15, row=(lane>>4)*4+j
  const int crow0 = gm + wr * 64 + (lane >> 4) * 4;
  const int ccol0 = gn + wc * 64 + l15;
  float sc_[4][4], sf_[4][4];
  if (MODE == 2) {
#pragma unroll
    for (int m = 0; m < 4; ++m)
#pragma unroll
      for (int j = 0; j < 4; ++j) {
        const int c = (crow0 + m * 16 + j) & 63;
        const float s = g2[c] * rsqrtf(v2[c] + EPSV);
        sc_[m][j] = s;
        sf_[m][j] = b2[c] - m2[c] * s;
      }
  }
#pragma unroll
  for (int m = 0; m < 4; ++m)
#pragma unroll
    for (int n = 0; n < 4; ++n) {
      const int col = ccol0 + n * 16;
      const float bv = bias ? bias[col] : 0.f;
#pragma unroll
      for (int j = 0; j < 4; ++j) {
        const int row = crow0 + m * 16 + j;
        float v = acc[m][n][j] + bv;
        if (MODE == 0) {
          ((float*)Cout)[(size_t)row * N + col] = v;
        } else if (MODE == 1) {
          ((ushort*)Cout)[(size_t)row * N + col] = f2bf(v);
        } else if (MODE == 2) {
          v = v * sc_[m][j] + sf_[m][j];
          ((ushort*)Cout)[(size_t)row * N + col] = f2bf(v);
        } else {  // MODE 3: kv split
          const ushort h = f2bf(v);
          if (col < 384) {
            kq[(size_t)row * 384 + col] = h;
          } else {
            vt[(size_t)(row >> 6) * 24576 + (size_t)(col - 384) * 64 +
               (row & 63)] = h;
          }
        }
      }
    }
}

// ---------------------------------------------------------------------------
// gemm_ga: ga[32768][8] = sigmoid(fea @ W_ga + b_ga), depth-3 pipeline,
// T2 swizzle both-sides. wave0 stages 3 loads/step, others 2 (per-wave vmcnt).
// ---------------------------------------------------------------------------
__global__ __launch_bounds__(256) void gemm_ga(
    const ushort* __restrict__ fea, const ushort* __restrict__ WTga,
    const float* __restrict__ b_ga, float* __restrict__ ga) {
  constexpr int K = EFn;
  __shared__ ushort sh[13824];  // 3 x (As 4096 | Bs 512)
  const int tid = threadIdx.x;
  const int wave = tid >> 6, lane = tid & 63;
  const int gm = blockIdx.x * 128;

  const int sws = ((tid & 3) ^ ((tid >> 3) & 3)) * 8;
  const int swsB = ((lane & 3) ^ ((lane >> 3) & 3)) * 8;
  const int c0 = tid, c1 = tid + 256;
  const ushort* gA0 = fea + (size_t)(gm + (c0 >> 2)) * K + sws;
  const ushort* gA1 = fea + (size_t)(gm + (c1 >> 2)) * K + sws;
  const ushort* gB = WTga + (size_t)(lane >> 2) * K + swsB;

  f32x4 acc[2] = {};
  const int l15 = lane & 15, l4 = lane >> 4;
  const int kswz = ((l4 ^ ((l15 >> 1) & 3))) * 8;
  constexpr int nk = K / 32;

#define GA_STAGE(buf, k0)                                     \
  {                                                           \
    load16(gA0 + (k0), &sh[(buf)*4608 + wave * 512]);         \
    load16(gA1 + (k0), &sh[(buf)*4608 + 2048 + wave * 512]);  \
    if (wave == 0) load16(gB + (k0), &sh[(buf)*4608 + 4096]); \
  }

  GA_STAGE(0, 0);
  GA_STAGE(1, 32);
  int bc = 0;
  for (int t = 0; t < nk; ++t) {
    if (t + 2 < nk) {
      const int bp = (bc == 0) ? 2 : bc - 1;
      GA_STAGE(bp, (t + 2) * 32);
      __builtin_amdgcn_sched_barrier(0);
      if (wave == 0)
        asm volatile("s_waitcnt vmcnt(6)" ::: "memory");
      else
        asm volatile("s_waitcnt vmcnt(4)" ::: "memory");
    } else if (t + 1 < nk) {
      if (wave == 0)
        asm volatile("s_waitcnt vmcnt(3)" ::: "memory");
      else
        asm volatile("s_waitcnt vmcnt(2)" ::: "memory");
    } else {
      asm volatile("s_waitcnt vmcnt(0)" ::: "memory");
    }
    __builtin_amdgcn_s_barrier();
    __builtin_amdgcn_sched_barrier(0);
    const short8 b = *reinterpret_cast<const short8*>(
        &sh[bc * 4608 + 4096 + l15 * 32 + kswz]);
    short8 a[2];
#pragma unroll
    for (int mi = 0; mi < 2; ++mi)
      a[mi] = *reinterpret_cast<const short8*>(
          &sh[bc * 4608 + (wave * 32 + mi * 16 + l15) * 32 + kswz]);
#pragma unroll
    for (int mi = 0; mi < 2; ++mi)
      acc[mi] =
          __builtin_amdgcn_mfma_f32_16x16x32_bf16(a[mi], b, acc[mi], 0, 0, 0);
    __builtin_amdgcn_s_barrier();
    __builtin_amdgcn_sched_barrier(0);
    bc = (bc == 2) ? 0 : bc + 1;
  }
#undef GA_STAGE

  if (l15 < 8) {
    const float bv = b_ga[l15];
#pragma unroll
    for (int mi = 0; mi < 2; ++mi)
#pragma unroll
      for (int j = 0; j < 4; ++j) {
        const int row = gm + wave * 32 + mi * 16 + l4 * 4 + j;
        const float v = acc[mi][j] + bv;
        ga[(size_t)row * 8 + l15] = 1.0f / (1.0f + expf(-v));
      }
  }
}

// ---------------------------------------------------------------------------
// gemm_sm: actT[512][32768] = softmax-epilogue( WT2 @ fea^T ), depth-3,
// gm-fastest XCD mapping, T2 swizzle. Fuses BN1 + group softmax + ga.
// ---------------------------------------------------------------------------
__global__ __launch_bounds__(256) void gemm_sm(
    const ushort* __restrict__ A, const ushort* __restrict__ BT,
    const float* __restrict__ g1, const float* __restrict__ b1,
    const float* __restrict__ m1, const float* __restrict__ v1,
    const float* __restrict__ ga, ushort* __restrict__ actT) {
  constexpr int K = EFn, N = Nrows;
  __shared__ ushort sh[24576];
  __shared__ float sScale[128], sShift[128];
  const int tid = threadIdx.x;
  const int wave = tid >> 6, lane = tid & 63;
  const int lid = xcd_lid();           // 0..1023
  const int gm = (lid & 3) * 128;      // gm fastest within XCD chunk
  const int gn = (lid >> 2) * 128;
  const int wr = wave >> 1, wc = wave & 1;

  if (tid < 128) {
    const int row = gm + tid;
    const float sc = g1[row] * rsqrtf(v1[row] + EPSV);
    sScale[tid] = sc;
    sShift[tid] = b1[row] - m1[row] * sc;
  }

  const int sws = ((tid & 3) ^ ((tid >> 3) & 3)) * 8;
  const int c0 = tid, c1 = tid + 256;
  const ushort* gA0 = A + (size_t)(gm + (c0 >> 2)) * K + sws;
  const ushort* gA1 = A + (size_t)(gm + (c1 >> 2)) * K + sws;
  const ushort* gB0 = BT + (size_t)(gn + (c0 >> 2)) * K + sws;
  const ushort* gB1 = BT + (size_t)(gn + (c1 >> 2)) * K + sws;

  f32x4 acc[4][4] = {};
  const int l15 = lane & 15;
  const int arow = wr * 64 + l15;
  const int brow = wc * 64 + l15;
  const int kswz = (((lane >> 4) ^ ((l15 >> 1) & 3))) * 8;
  constexpr int nk = K >> 5;

#define SM_STAGE(buf, k0)                                    \
  {                                                          \
    load16(gA0 + (k0), &sh[(buf)*8192 + wave * 512]);        \
    load16(gA1 + (k0), &sh[(buf)*8192 + 2048 + wave * 512]); \
    load16(gB0 + (k0), &sh[(buf)*8192 + 4096 + wave * 512]); \
    load16(gB1 + (k0), &sh[(buf)*8192 + 6144 + wave * 512]); \
  }

  SM_STAGE(0, 0);
  SM_STAGE(1, 32);
  int bc = 0;
  for (int t = 0; t < nk; ++t) {
    if (t + 2 < nk) {
      const int bp = (bc == 0) ? 2 : bc - 1;
      SM_STAGE(bp, (t + 2) * 32);
      __builtin_amdgcn_sched_barrier(0);
      asm volatile("s_waitcnt vmcnt(8)" ::: "memory");
    } else if (t + 1 < nk) {
      asm volatile("s_waitcnt vmcnt(4)" ::: "memory");
    } else {
      asm volatile("s_waitcnt vmcnt(0)" ::: "memory");
    }
    __builtin_amdgcn_s_barrier();
    __builtin_amdgcn_sched_barrier(0);
    short8 a[4], b[4];
#pragma unroll
    for (int m = 0; m < 4; ++m)
      a[m] = *reinterpret_cast<const short8*>(
          &sh[bc * 8192 + (arow + m * 16) * 32 + kswz]);
#pragma unroll
    for (int n = 0; n < 4; ++n)
      b[n] = *reinterpret_cast<const short8*>(
          &sh[bc * 8192 + 4096 + (brow + n * 16) * 32 + kswz]);
#pragma unroll
    for (int m = 0; m < 4; ++m)
#pragma unroll
      for (int n = 0; n < 4; ++n)
        acc[m][n] = __builtin_amdgcn_mfma_f32_16x16x32_bf16(
            a[m], b[n], acc[m][n], 0, 0, 0);
    __builtin_amdgcn_s_barrier();
    __builtin_amdgcn_sched_barrier(0);
    bc = (bc == 2) ? 0 : bc + 1;
  }
#undef SM_STAGE

  const int l4 = lane >> 4;
  const int g = (gm >> 6) + wr;
#pragma unroll
  for (int n = 0; n < 4; ++n) {
    const int col = gn + wc * 64 + n * 16 + l15;
    float mx = -1e30f;
#pragma unroll
    for (int m = 0; m < 4; ++m)
#pragma unroll
      for (int j = 0; j < 4; ++j) {
        const int rl = wr * 64 + m * 16 + l4 * 4 + j;
        acc[m][n][j] = acc[m][n][j] * sScale[rl] + sShift[rl];
        mx = fmaxf(mx, acc[m][n][j]);
      }
    mx = fmaxf(mx, __shfl_xor(mx, 16));
    mx = fmaxf(mx, __shfl_xor(mx, 32));
    float sum = 0.f;
#pragma unroll
    for (int m = 0; m < 4; ++m)
#pragma unroll
      for (int j = 0; j < 4; ++j) {
        acc[m][n][j] = expf(acc[m][n][j] - mx);
        sum += acc[m][n][j];
      }
    sum += __shfl_xor(sum, 16);
    sum += __shfl_xor(sum, 32);
    const float sc = ga[(size_t)col * 8 + g] / sum;
#pragma unroll
    for (int m = 0; m < 4; ++m)
#pragma unroll
      for (int j = 0; j < 4; ++j) {
        const int rowg = gm + wr * 64 + m * 16 + l4 * 4 + j;
        actT[(size_t)rowg * N + col] = f2bf(acc[m][n][j] * sc);
      }
  }
}

// ---------------------------------------------------------------------------
__global__ __launch_bounds__(256) void cvt_kernel(const float* __restrict__ in,
                                                  ushort* __restrict__ out,
                                                  int n4) {
  const int i = blockIdx.x * 256 + threadIdx.x;
  if (i >= n4) return;
  const float4 v = reinterpret_cast<const float4*>(in)[i];
  ushort4 o;
  o.x = f2bf(v.x); o.y = f2bf(v.y); o.z = f2bf(v.z); o.w = f2bf(v.w);
  reinterpret_cast<ushort4*>(out)[i] = o;
}

// ---------------------------------------------------------------------------
// transpose + convert: in f32 [R][C] -> out bf16 [C][R]
// ---------------------------------------------------------------------------
__global__ __launch_bounds__(256) void tconv_kernel(const float* __restrict__ in,
                                                    ushort* __restrict__ out,
                                                    int R, int C) {
  __shared__ float t[32][33];
  const int tx = threadIdx.x & 31, ty = threadIdx.x >> 5;
  const int bc = blockIdx.x * 32, br = blockIdx.y * 32;
#pragma unroll
  for (int i = 0; i < 32; i += 8)
    t[ty + i][tx] = in[(size_t)(br + ty + i) * C + bc + tx];
  __syncthreads();
#pragma unroll
  for (int i = 0; i < 32; i += 8)
    out[(size_t)(bc + ty + i) * R + br + tx] = f2bf(t[tx][ty + i]);
}

// ---------------------------------------------------------------------------
// W_ga [1536][8] f32 -> WTga [16][1536] bf16 (rows 8..15 zero)
// ---------------------------------------------------------------------------
__global__ __launch_bounds__(256) void gawt_kernel(const float* __restrict__ in,
                                                   ushort* __restrict__ out) {
  const int k = blockIdx.x * 256 + threadIdx.x;  // 0..1535
#pragma unroll
  for (int g = 0; g < 8; ++g) {
    out[(size_t)g * EFn + k] = f2bf(in[(size_t)k * 8 + g]);
    out[(size_t)(g + 8) * EFn + k] = 0;
  }
}

// ---------------------------------------------------------------------------
// cent_mfma: block per (b,g,ch). part[bid][c=64][f=192], K=512 over s.
// A = actT rows (s-contiguous, as before). B now read DIRECTLY from fea
// [s][ef]: each of 192 threads loads an 8s x 8ef subtile (8 x uint4,
// coalesced along ef) and writes it TRANSPOSED into the XOR-swizzled LDS
// tile via in-register 8x8 transpose + 8 x ds_write_b128. Fragment reads
// unchanged. This removes the 100 MB feaT materialization entirely.
// ---------------------------------------------------------------------------
__global__ __launch_bounds__(256) void cent_mfma(
    const ushort* __restrict__ actT, const ushort* __restrict__ fea,
    float* __restrict__ part) {
  __shared__ ushort As[2][64 * 64];
  __shared__ ushort Bs[2][192 * 64];
  const int tid = threadIdx.x;
  const int wave = tid >> 6, lane = tid & 63;
  const int b = blockIdx.x >> 4;
  const int g = (blockIdx.x >> 1) & 7;
  const int ch = blockIdx.x & 1;
  const size_t colbase = (size_t)b * 1024 + ch * 512;  // global n of s-chunk
  const int srow = tid >> 2, scp = (tid & 3) * 2;
  const ushort* gA = actT + (size_t)(g * 64 + srow) * Nrows + colbase;
  // B staging task split: threads 0..191
  const int bseg = tid % 24;  // ef-segment (8 ef)
  const int bsg = tid / 24;   // s-group (8 s), 0..7 for active threads
  const bool bact = tid < 192;
  const ushort* gB =
      fea + (size_t)(colbase + bsg * 8) * EFn + g * 192 + bseg * 8;

  uint4 ra[2], rbv[8];
  f32x4 acc[4][3] = {};
  const int l15 = lane & 15, hi = lane >> 4;
  const int sw = srow & 7;

#define CM_ISSUE(k0)                                                        \
  {                                                                         \
    _Pragma("unroll") for (int i = 0; i < 2; ++i) ra[i] =                   \
        *reinterpret_cast<const uint4*>(gA + (k0) + (scp + i) * 8);         \
    if (bact) {                                                             \
      _Pragma("unroll") for (int i = 0; i < 8; ++i) rbv[i] =                \
          *reinterpret_cast<const uint4*>(gB + (size_t)((k0) + i) * EFn);   \
    }                                                                       \
  }
#define CM_STASH(buf)                                                       \
  {                                                                         \
    _Pragma("unroll") for (int i = 0; i < 2; ++i) {                         \
      const int c = scp + i;                                                \
      *reinterpret_cast<uint4*>(&As[buf][srow * 64 + ((c ^ sw) * 8)]) =     \
          ra[i];                                                            \
    }                                                                       \
    if (bact) {                                                             \
      const ushort* rin = reinterpret_cast<const ushort*>(rbv);             \
      _Pragma("unroll") for (int e = 0; e < 8; ++e) {                       \
        alignas(16) ushort tmp[8];                                          \
        _Pragma("unroll") for (int i = 0; i < 8; ++i) tmp[i] =              \
            rin[i * 8 + e];                                                 \
        const int r = bseg * 8 + e;                                         \
        *reinterpret_cast<uint4*>(&Bs[buf][r * 64 + ((bsg ^ (r & 7)) * 8)]) \
            = *reinterpret_cast<const uint4*>(tmp);                         \
      }                                                                     \
    }                                                                       \
  }

  CM_ISSUE(0);
  CM_STASH(0);
  for (int kk = 0; kk < 8; ++kk) {
    const int buf = kk & 1;
    __syncthreads();
    if (kk < 7) CM_ISSUE((kk + 1) * 64);
#pragma unroll
    for (int ks = 0; ks < 2; ++ks) {
      const int chh = ks * 4 + hi;
      short8 a[4], bb[3];
#pragma unroll
      for (int m = 0; m < 4; ++m) {
        const int r = m * 16 + l15;
        a[m] = *reinterpret_cast<const short8*>(
            &As[buf][r * 64 + ((chh ^ (r & 7)) * 8)]);
      }
#pragma unroll
      for (int nn = 0; nn < 3; ++nn) {
        const int r = wave * 48 + nn * 16 + l15;
        bb[nn] = *reinterpret_cast<const short8*>(
            &Bs[buf][r * 64 + ((chh ^ (r & 7)) * 8)]);
      }
#pragma unroll
      for (int m = 0; m < 4; ++m)
#pragma unroll
        for (int nn = 0; nn < 3; ++nn)
          acc[m][nn] = __builtin_amdgcn_mfma_f32_16x16x32_bf16(
              a[m], bb[nn], acc[m][nn], 0, 0, 0);
    }
    if (kk < 7) CM_STASH(buf ^ 1);
  }
#undef CM_ISSUE
#undef CM_STASH

  float* pb = part + (size_t)blockIdx.x * 12288;
#pragma unroll
  for (int m = 0; m < 4; ++m)
#pragma unroll
    for (int nn = 0; nn < 3; ++nn) {
      const int col = wave * 48 + nn * 16 + l15;
#pragma unroll
      for (int j = 0; j < 4; ++j) {
        const int row = m * 16 + hi * 4 + j;
        pb[row * 192 + col] = acc[m][nn][j];
      }
    }
}

// reduce over (g,ch) -> cent bf16 [2048][192]
__global__ __launch_bounds__(256) void cent_reduce8(
    const float* __restrict__ part, ushort* __restrict__ cent) {
  const int idx = blockIdx.x * 256 + threadIdx.x;  // < 393216
  const int b = idx / 12288, r = idx % 12288;
  float s = 0.f;
#pragma unroll
  for (int j = 0; j < 16; ++j) s += part[(size_t)(b * 16 + j) * 12288 + r];
  cent[idx] = f2bf(s);
}

// ---------------------------------------------------------------------------
// MFMA attention (verified R3): one wave per 32 q-rows, all-register.
// ---------------------------------------------------------------------------
__global__ __launch_bounds__(256) void attn_mfma(
    const ushort* __restrict__ qb, const ushort* __restrict__ kb,
    const ushort* __restrict__ vtb, ushort* __restrict__ aout) {
  const int wave = threadIdx.x >> 6, lane = threadIdx.x & 63;
  const int wrow = blockIdx.x * 4 + wave;
  const int row0 = wrow * 32;
  const int b = row0 >> 10;
  const int l31 = lane & 31, hi = lane >> 5;

  f32x16 accs0 = 0.f, accs1 = 0.f;
  const ushort* qp = qb + (size_t)(row0 + l31) * 384 + hi * 8;
  const ushort* kp = kb + (size_t)(b * 64 + l31) * 384 + hi * 8;
#pragma unroll 4
  for (int ks = 0; ks < 24; ++ks) {
    const short8 bq = *reinterpret_cast<const short8*>(qp + ks * 16);
    const short8 a0 = *reinterpret_cast<const short8*>(kp + ks * 16);
    const short8 a1 = *reinterpret_cast<const short8*>(kp + 32 * 384 + ks * 16);
    accs0 = __builtin_amdgcn_mfma_f32_32x32x16_bf16(a0, bq, accs0, 0, 0, 0);
    accs1 = __builtin_amdgcn_mfma_f32_32x32x16_bf16(a1, bq, accs1, 0, 0, 0);
  }

  const float alpha = 0.05103103630798287f;
  float p[32];
#pragma unroll
  for (int i = 0; i < 16; ++i) { p[i] = accs0[i]; p[16 + i] = accs1[i]; }
  float mx = p[0];
#pragma unroll
  for (int i = 1; i < 32; ++i) mx = fmaxf(mx, p[i]);
  mx = fmaxf(mx, __shfl_xor(mx, 32));
  float sum = 0.f;
#pragma unroll
  for (int i = 0; i < 32; ++i) {
    p[i] = expf((p[i] - mx) * alpha);
    sum += p[i];
  }
  sum += __shfl_xor(sum, 32);
  const float inv = 1.0f / sum;

  uint pk0[8], pk1[8];
#pragma unroll
  for (int ct = 0; ct < 2; ++ct)
#pragma unroll
    for (int rg = 0; rg < 4; ++rg) {
      pk0[ct * 4 + rg] =
          pack2bf(p[ct * 16 + rg * 4 + 0] * inv, p[ct * 16 + rg * 4 + 1] * inv);
      pk1[ct * 4 + rg] =
          pack2bf(p[ct * 16 + rg * 4 + 2] * inv, p[ct * 16 + rg * 4 + 3] * inv);
    }
  uint ex0[8], ex1[8];
#pragma unroll
  for (int i = 0; i < 8; ++i) {
    ex0[i] = __shfl_xor(pk0[i], 32);
    ex1[i] = __shfl_xor(pk1[i], 32);
  }

  const ushort* vp = vtb + ((size_t)b * 384 + l31) * 64 + hi * 8;
  ushort* orow = aout + (size_t)(row0 + l31) * 384;
  for (int mt = 0; mt < 12; ++mt) {
    f32x16 acco = 0.f;
#pragma unroll
    for (int kc = 0; kc < 4; ++kc) {
      const short8 av = *reinterpret_cast<const short8*>(
          vp + (size_t)mt * 32 * 64 + kc * 16);
      const int base = (kc >> 1) * 4 + (kc & 1) * 2;
      const uint o0 = hi ? pk0[base + 1] : pk0[base];
      const uint o1 = hi ? pk1[base + 1] : pk1[base];
      const uint e0 = hi ? ex0[base + 1] : ex0[base];
      const uint e1 = hi ? ex1[base + 1] : ex1[base];
      uint4 uu;
      uu.x = hi ? e0 : o0;
      uu.y = hi ? e1 : o1;
      uu.z = hi ? o0 : e0;
      uu.w = hi ? o1 : e1;
      const short8 bp = __builtin_bit_cast(short8, uu);
      acco = __builtin_amdgcn_mfma_f32_32x32x16_bf16(av, bp, acco, 0, 0, 0);
    }
#pragma unroll
    for (int rg = 0; rg < 4; ++rg) {
      ushort4 ov;
      ov.x = f2bf(acco[rg * 4 + 0]);
      ov.y = f2bf(acco[rg * 4 + 1]);
      ov.z = f2bf(acco[rg * 4 + 2]);
      ov.w = f2bf(acco[rg * 4 + 3]);
      *reinterpret_cast<ushort4*>(&orow[mt * 32 + rg * 8 + hi * 4]) = ov;
    }
  }
}

// ---------------------------------------------------------------------------
extern "C" void kernel_launch(void* const* d_in, const int* in_sizes, int n_in,
                              void* d_out, int out_size, void* d_ws,
                              size_t ws_size, hipStream_t stream) {
  (void)in_sizes; (void)n_in; (void)out_size; (void)ws_size;
  const float* x      = (const float*)d_in[0];
  const float* W_exp  = (const float*)d_in[1];
  const float* b_exp  = (const float*)d_in[2];
  const float* W_ga   = (const float*)d_in[3];
  const float* b_ga   = (const float*)d_in[4];
  const float* bn1_g  = (const float*)d_in[5];
  const float* bn1_b  = (const float*)d_in[6];
  const float* bn1_m  = (const float*)d_in[7];
  const float* bn1_v  = (const float*)d_in[8];
  const float* cw     = (const float*)d_in[9];
  const float* W_proj = (const float*)d_in[10];
  const float* b_proj = (const float*)d_in[11];
  const float* bn2_g  = (const float*)d_in[12];
  const float* bn2_b  = (const float*)d_in[13];
  const float* bn2_m  = (const float*)d_in[14];
  const float* bn2_v  = (const float*)d_in[15];
  const float* Wq     = (const float*)d_in[16];
  const float* bq     = (const float*)d_in[17];
  const float* Wkv    = (const float*)d_in[18];
  const float* bkv    = (const float*)d_in[19];
  const float* Wp2    = (const float*)d_in[20];
  const float* bp2    = (const float*)d_in[21];
  float* out = (float*)d_out;

  char* ws = (char*)d_ws;
  // region A @0: fea bf16 100.66MB (last read: cent step 6);
  //              aout bf16 25.2MB reuses it after (step 9)
  ushort* fea  = (ushort*)(ws + 0);
  ushort* aout = (ushort*)(ws + 0);
  // region B: xb 50.3MB (last read: q GEMM step 3); actT 33.6MB reuses it
  ushort* xb   = (ushort*)(ws + 100663296ull);
  ushort* actT = (ushort*)(ws + 100663296ull);
  ushort* q_bf = (ushort*)(ws + 150994944ull);  // 25.2MB
  float*  ga   = (float*)(ws + 176160768ull);   // 1MB
  float*  part = (float*)(ws + 177209344ull);   // 25.2MB (512 x 12288 f32)
  ushort* WT1  = (ushort*)(ws + 202375168ull);  // W_exp^T  [1536][768]
  ushort* WT2  = (ushort*)(ws + 204734464ull);  // cw^T     [512][1536]
  ushort* WT3  = (ushort*)(ws + 206307328ull);  // Wq^T     [384][768]
  ushort* WT4  = (ushort*)(ws + 206897152ull);  // Wp2^T    [768][384]
  ushort* WT5  = (ushort*)(ws + 207486976ull);  // W_proj^T [768][192]
  ushort* WT6  = (ushort*)(ws + 207781888ull);  // Wkv^T    [768][768]
  ushort* WTga = (ushort*)(ws + 208961536ull);  // W_ga^T   [16][1536]
  ushort* cent = (ushort*)(ws + 209010688ull);  // [2048][192] bf16
  ushort* nc   = (ushort*)(ws + 209797120ull);  // [2048][768] bf16
  ushort* k_bf = (ushort*)(ws + 212942848ull);  // [2048][384] bf16
  ushort* vT_bf= (ushort*)(ws + 214515712ull);  // [32][384][64] bf16

  dim3 blk(256);
  // 1. conversions / weight transposes
  cvt_kernel<<<dim3((Nrows * Dn / 4 + 255) / 256), blk, 0, stream>>>(
      x, xb, Nrows * Dn / 4);
  tconv_kernel<<<dim3(EFn / 32, Dn / 32), blk, 0, stream>>>(W_exp, WT1, Dn, EFn);
  tconv_kernel<<<dim3(512 / 32, EFn / 32), blk, 0, stream>>>(cw, WT2, EFn, 512);
  tconv_kernel<<<dim3(Pn / 32, Dn / 32), blk, 0, stream>>>(Wq, WT3, Dn, Pn);
  tconv_kernel<<<dim3(Dn / 32, Pn / 32), blk, 0, stream>>>(Wp2, WT4, Pn, Dn);
  tconv_kernel<<<dim3(Dn / 32, GFSn / 32), blk, 0, stream>>>(W_proj, WT5, GFSn, Dn);
  tconv_kernel<<<dim3(Dn / 32, Dn / 32), blk, 0, stream>>>(Wkv, WT6, Dn, Dn);
  gawt_kernel<<<dim3(EFn / 256), blk, 0, stream>>>(W_ga, WTga);
  // 2. fea = bf16(x @ W_exp + b_exp)   (single output, no feaT)
  gemm_bf16<1><<<dim3(EFn / 128, Nrows / 128), blk, 0, stream>>>(
      xb, WT1, b_exp, fea, Nrows, EFn, Dn,
      nullptr, nullptr, nullptr, nullptr, nullptr, nullptr);
  // 3. q = bf16(x @ Wq + bq)   (last consumer of xb)
  gemm_bf16<1><<<dim3(Pn / 128, Nrows / 128), blk, 0, stream>>>(
      xb, WT3, bq, q_bf, Nrows, Pn, Dn,
      nullptr, nullptr, nullptr, nullptr, nullptr, nullptr);
  // 4. ga = sigmoid(fea @ W_ga + b_ga)
  gemm_ga<<<dim3(Nrows / 128), blk, 0, stream>>>(fea, WTga, b_ga, ga);
  // 5. actT = softmax-gemm(cw^T @ fea^T)
  gemm_sm<<<dim3(Nrows / 128, 512 / 128), blk, 0, stream>>>(
      WT2, fea, bn1_g, bn1_b, bn1_m, bn1_v, ga, actT);
  // 6. cent = sum_g actT_g @ fea_g (B transposed on read)  -> bf16
  cent_mfma<<<dim3(Bn * Gn * 2), blk, 0, stream>>>(actT, fea, part);
  cent_reduce8<<<dim3(393216 / 256), blk, 0, stream>>>(part, cent);
  // 7. nc = bf16(BN2(cent @ W_proj + b_proj))   (M=2048,N=768,K=192)
  gemm_bf16<2><<<dim3(Dn / 128, 2048 / 128), blk, 0, stream>>>(
      cent, WT5, b_proj, nc, 2048, Dn, GFSn,
      bn2_g, bn2_b, bn2_m, bn2_v, nullptr, nullptr);
  // 8. kv = nc @ Wkv + bkv -> k_bf, vT_bf   (M=2048,N=768,K=768)
  gemm_bf16<3><<<dim3(Dn / 128, 2048 / 128), blk, 0, stream>>>(
      nc, WT6, bkv, nullptr, 2048, Dn, Dn,
      nullptr, nullptr, nullptr, nullptr, k_bf, vT_bf);
  // 9. attention
  attn_mfma<<<dim3(Nrows / 128), blk, 0, stream>>>(q_bf, k_bf, vT_bf, aout);
  // 10. out = aout @ Wp2 + bp2
  gemm_bf16<0><<<dim3(Dn / 128, Nrows / 128), blk, 0, stream>>>(
      aout, WT4, bp2, out, Nrows, Dn, Pn,
      nullptr, nullptr, nullptr, nullptr, nullptr, nullptr);
}